// Round 2
// baseline (6101.774 us; speedup 1.0000x reference)
//
#include <hip/hip_runtime.h>

// ---------------------------------------------------------------------------
// AgentAttention forward, f32 baseline.
// B=16, CIN=3, H=W=64, n=4096, C=512, NH=16, hd=32, AGENT=49
// token t = w*64 + h (reference flattens (W,H)); reshape axes A1=t>>6, A2=t&63
// ---------------------------------------------------------------------------

// ---- qkv GEMM fused with 1x1 input projection -----------------------------
// A[r, kk] = in_b[kk] + sum_i x[b,i,h_,w_] * in_w[i,kk],  r=(b,t), sp swizzled
// B = qkv_w (512 x 1536).  C split into q,k,v (each (b,n,512)).
__global__ __launch_bounds__(256) void qkv_gemm(
    const float* __restrict__ x, const float* __restrict__ in_w,
    const float* __restrict__ in_b, const float* __restrict__ qkv_w,
    const float* __restrict__ qkv_b,
    float* __restrict__ q, float* __restrict__ k, float* __restrict__ v)
{
  __shared__ float As[16][64];
  __shared__ float Bs[16][64];
  const int tid = threadIdx.x;
  const int tx = tid & 15, ty = tid >> 4;
  const int rowBase = blockIdx.y * 64;
  const int colBase = blockIdx.x * 64;

  // A-tile loader mapping: 64 rows x 16 k, 4 k per thread
  const int lr = tid >> 2;           // 0..63 row in tile
  const int lc = (tid & 3) * 4;      // k offset 0,4,8,12
  const int R  = rowBase + lr;
  const int bb = R >> 12, t = R & 4095;
  const int sp = ((t & 63) << 6) | (t >> 6);     // x spatial swizzle
  const float x0 = x[(size_t)(bb * 3 + 0) * 4096 + sp];
  const float x1 = x[(size_t)(bb * 3 + 1) * 4096 + sp];
  const float x2 = x[(size_t)(bb * 3 + 2) * 4096 + sp];

  // B-tile loader mapping: 16 k-rows x 64 cols, 4 cols per thread
  const int br = tid >> 4;           // 0..15
  const int bc = (tid & 15) * 4;     // 0..60

  float acc[4][4];
#pragma unroll
  for (int i = 0; i < 4; ++i)
#pragma unroll
    for (int j = 0; j < 4; ++j) acc[i][j] = 0.f;

  for (int k0 = 0; k0 < 512; k0 += 16) {
    const int kb = k0 + lc;
    float4 w0 = *(const float4*)&in_w[kb];
    float4 w1 = *(const float4*)&in_w[512 + kb];
    float4 w2 = *(const float4*)&in_w[1024 + kb];
    float4 b4 = *(const float4*)&in_b[kb];
    As[lc + 0][lr] = b4.x + x0 * w0.x + x1 * w1.x + x2 * w2.x;
    As[lc + 1][lr] = b4.y + x0 * w0.y + x1 * w1.y + x2 * w2.y;
    As[lc + 2][lr] = b4.z + x0 * w0.z + x1 * w1.z + x2 * w2.z;
    As[lc + 3][lr] = b4.w + x0 * w0.w + x1 * w1.w + x2 * w2.w;
    *(float4*)&Bs[br][bc] =
        *(const float4*)&qkv_w[(size_t)(k0 + br) * 1536 + colBase + bc];
    __syncthreads();
#pragma unroll
    for (int kk = 0; kk < 16; ++kk) {
      float4 a4 = *(const float4*)&As[kk][ty * 4];
      float4 bv = *(const float4*)&Bs[kk][tx * 4];
      acc[0][0] += a4.x * bv.x; acc[0][1] += a4.x * bv.y;
      acc[0][2] += a4.x * bv.z; acc[0][3] += a4.x * bv.w;
      acc[1][0] += a4.y * bv.x; acc[1][1] += a4.y * bv.y;
      acc[1][2] += a4.y * bv.z; acc[1][3] += a4.y * bv.w;
      acc[2][0] += a4.z * bv.x; acc[2][1] += a4.z * bv.y;
      acc[2][2] += a4.z * bv.z; acc[2][3] += a4.z * bv.w;
      acc[3][0] += a4.w * bv.x; acc[3][1] += a4.w * bv.y;
      acc[3][2] += a4.w * bv.z; acc[3][3] += a4.w * bv.w;
    }
    __syncthreads();
  }

  const int gc0 = colBase + tx * 4;      // tile never straddles q/k/v (64|512)
  float* dst; int lc0;
  if (gc0 < 512)       { dst = q; lc0 = gc0; }
  else if (gc0 < 1024) { dst = k; lc0 = gc0 - 512; }
  else                 { dst = v; lc0 = gc0 - 1024; }
  float4 bias = *(const float4*)&qkv_b[gc0];
#pragma unroll
  for (int i = 0; i < 4; ++i) {
    const int Rw = rowBase + ty * 4 + i;
    float4 wv;
    wv.x = acc[i][0] + bias.x; wv.y = acc[i][1] + bias.y;
    wv.z = acc[i][2] + bias.z; wv.w = acc[i][3] + bias.w;
    *(float4*)&dst[(size_t)Rw * 512 + lc0] = wv;
  }
}

// ---- adaptive avg pool q -> qt (b,49,512); every window is 10x10 ----------
__global__ __launch_bounds__(256) void pool_qt(const float* __restrict__ q,
                                               float* __restrict__ qt)
{
  const int blk = blockIdx.x;
  const int a = blk % 49, b = blk / 49;
  const int iA = a / 7, iB = a % 7;
  const int sA = (iA * 64) / 7, eA = ((iA + 1) * 64 + 6) / 7;
  const int sB = (iB * 64) / 7, eB = ((iB + 1) * 64 + 6) / 7;
  const float invn = 1.0f / (float)((eA - sA) * (eB - sB));
  for (int c = threadIdx.x; c < 512; c += 256) {
    float s = 0.f;
    for (int A = sA; A < eA; ++A)
      for (int Bb = sB; Bb < eB; ++Bb)
        s += q[((size_t)b * 4096 + A * 64 + Bb) * 512 + c];
    qt[((size_t)b * 49 + a) * 512 + c] = s * invn;
  }
}

// ---- bias precompute: bilinear resize 7x7 -> 64x64 + positional biases ----
// bias1[h,a,t] = resize(an)[h,a,t] + ah[h,a,tA] + aw[h,a,tB]
// bias2[h,t,a] = resize(na)[h,a,t] + ha[h,tA,a] + wa[h,tB,a]
__global__ __launch_bounds__(256) void bias_prep(
    const float* __restrict__ an, const float* __restrict__ na,
    const float* __restrict__ ah, const float* __restrict__ aw,
    const float* __restrict__ ha, const float* __restrict__ wa,
    float* __restrict__ bias1, float* __restrict__ bias2)
{
  const int blk = blockIdx.x;
  const int a = blk % 49, h = blk / 49;
  const float* anp = an + (size_t)(h * 49 + a) * 49;
  const float* nap = na + (size_t)(h * 49 + a) * 49;
  for (int t = threadIdx.x; t < 4096; t += 256) {
    const int tA = t >> 6, tB = t & 63;
    float cA = (tA + 0.5f) * 0.109375f - 0.5f;
    cA = fminf(fmaxf(cA, 0.f), 6.f);
    int i0A = (int)floorf(cA); float wA = cA - (float)i0A;
    int i1A = min(i0A + 1, 6);
    float cB = (tB + 0.5f) * 0.109375f - 0.5f;
    cB = fminf(fmaxf(cB, 0.f), 6.f);
    int i0B = (int)floorf(cB); float wB = cB - (float)i0B;
    int i1B = min(i0B + 1, 6);

    float v1 = (1.f - wA) * ((1.f - wB) * anp[i0A * 7 + i0B] + wB * anp[i0A * 7 + i1B]) +
               wA        * ((1.f - wB) * anp[i1A * 7 + i0B] + wB * anp[i1A * 7 + i1B]);
    float v2 = (1.f - wA) * ((1.f - wB) * nap[i0A * 7 + i0B] + wB * nap[i0A * 7 + i1B]) +
               wA        * ((1.f - wB) * nap[i1A * 7 + i0B] + wB * nap[i1A * 7 + i1B]);

    bias1[((size_t)h * 49 + a) * 4096 + t] =
        v1 + ah[(size_t)(h * 49 + a) * 64 + tA] + aw[(size_t)(h * 49 + a) * 64 + tB];
    bias2[((size_t)h * 4096 + t) * 49 + a] =
        v2 + ha[((size_t)h * 64 + tA) * 49 + a] + wa[((size_t)h * 64 + tB) * 49 + a];
  }
}

// ---- stage 1: agent->token attention, one block per (b,h,agent) row -------
__global__ __launch_bounds__(256) void stage1(
    const float* __restrict__ qt, const float* __restrict__ k,
    const float* __restrict__ v, const float* __restrict__ bias1,
    float* __restrict__ agent_v)
{
  __shared__ float sc[4096];
  __shared__ float red[256];
  __shared__ float qsh[32];
  const int blk = blockIdx.x;
  const int a = blk % 49;
  const int bh = blk / 49;
  const int h = bh & 15, b = bh >> 4;
  const int tid = threadIdx.x;

  if (tid < 32)
    qsh[tid] = qt[((size_t)b * 49 + a) * 512 + h * 32 + tid] * 0.17677669529663689f;
  __syncthreads();
  float qr[32];
#pragma unroll
  for (int d = 0; d < 32; ++d) qr[d] = qsh[d];

  const float* kb = k + (size_t)b * 4096 * 512 + h * 32;
  const float* b1 = bias1 + ((size_t)h * 49 + a) * 4096;
  float lmax = -3.0e38f;
  for (int t = tid; t < 4096; t += 256) {
    const float* kr = kb + (size_t)t * 512;
    float s = 0.f;
#pragma unroll
    for (int d4 = 0; d4 < 32; d4 += 4) {
      float4 f = *(const float4*)&kr[d4];
      s += qr[d4] * f.x + qr[d4 + 1] * f.y + qr[d4 + 2] * f.z + qr[d4 + 3] * f.w;
    }
    s += b1[t];
    sc[t] = s;
    lmax = fmaxf(lmax, s);
  }
  red[tid] = lmax; __syncthreads();
  for (int off = 128; off > 0; off >>= 1) {
    if (tid < off) red[tid] = fmaxf(red[tid], red[tid + off]);
    __syncthreads();
  }
  const float m = red[0];
  __syncthreads();
  float lsum = 0.f;
  for (int t = tid; t < 4096; t += 256) {
    float p = __expf(sc[t] - m);
    sc[t] = p;
    lsum += p;
  }
  red[tid] = lsum; __syncthreads();
  for (int off = 128; off > 0; off >>= 1) {
    if (tid < off) red[tid] += red[tid + off];
    __syncthreads();
  }
  const float S = red[0];
  __syncthreads();

  const int g = tid >> 5, d = tid & 31;
  const float* vb = v + (size_t)b * 4096 * 512 + h * 32 + d;
  float acc = 0.f;
  for (int t = g * 512; t < (g + 1) * 512; ++t)
    acc += sc[t] * vb[(size_t)t * 512];
  red[tid] = acc; __syncthreads();
  if (tid < 32) {
    float s2 = 0.f;
#pragma unroll
    for (int gg = 0; gg < 8; ++gg) s2 += red[gg * 32 + tid];
    agent_v[(((size_t)b * 16 + h) * 49 + a) * 32 + tid] = s2 / S;
  }
}

// ---- stage 2: token->agent attention + depthwise 3x3 conv + residual -----
// one thread per (h, t); block handles 16 tokens x 16 heads; o aliases q.
__global__ __launch_bounds__(256) void stage2(
    const float* __restrict__ q, const float* __restrict__ v,
    const float* __restrict__ qt, const float* __restrict__ agent_v,
    const float* __restrict__ bias2, const float* __restrict__ dwc_w,
    const float* __restrict__ dwc_b, float* __restrict__ o)
{
  __shared__ float sS[256 * 49];
  const int tid = threadIdx.x;
  const int h = tid & 15, tl = tid >> 4;
  const int blk = blockIdx.x;
  const int b = blk >> 8;
  const int t = (blk & 255) * 16 + tl;
  const float scale = 0.17677669529663689f;

  const size_t qoff = ((size_t)(b * 4096 + t)) * 512 + h * 32;
  float qr[32];
#pragma unroll
  for (int d4 = 0; d4 < 32; d4 += 4) {
    float4 f = *(const float4*)&q[qoff + d4];
    qr[d4] = f.x * scale; qr[d4 + 1] = f.y * scale;
    qr[d4 + 2] = f.z * scale; qr[d4 + 3] = f.w * scale;
  }

  float* srow = &sS[tid * 49];
  const float* qtb = qt + (size_t)b * 49 * 512 + h * 32;
  const float* b2 = bias2 + ((size_t)h * 4096 + t) * 49;
  float m = -3.0e38f;
  for (int a = 0; a < 49; ++a) {
    const float* qa = qtb + (size_t)a * 512;
    float s = 0.f;
#pragma unroll
    for (int d4 = 0; d4 < 32; d4 += 4) {
      float4 f = *(const float4*)&qa[d4];
      s += qr[d4] * f.x + qr[d4 + 1] * f.y + qr[d4 + 2] * f.z + qr[d4 + 3] * f.w;
    }
    s += b2[a];
    srow[a] = s;
    m = fmaxf(m, s);
  }
  float S = 0.f;
  for (int a = 0; a < 49; ++a) {
    float p = __expf(srow[a] - m);
    srow[a] = p;
    S += p;
  }
  const float inv = 1.0f / S;

  float acc[32];
#pragma unroll
  for (int d = 0; d < 32; ++d) acc[d] = dwc_b[h * 32 + d];

  // attention PV (probabilities pre-normalized)
  const float* avb = agent_v + ((size_t)(b * 16 + h)) * 49 * 32;
  for (int a = 0; a < 49; ++a) {
    const float pn = srow[a] * inv;
    const float* av = avb + a * 32;
#pragma unroll
    for (int d4 = 0; d4 < 32; d4 += 4) {
      float4 f = *(const float4*)&av[d4];
      acc[d4] += pn * f.x; acc[d4 + 1] += pn * f.y;
      acc[d4 + 2] += pn * f.z; acc[d4 + 3] += pn * f.w;
    }
  }

  // depthwise 3x3 conv on v (token grid A1=t>>6, A2=t&63, zero pad)
  const int A = t >> 6, Bc = t & 63;
  const float* wc = dwc_w + (size_t)(h * 32) * 9;
  for (int di = -1; di <= 1; ++di) {
    const int An = A + di;
    if (An < 0 || An > 63) continue;
    for (int dj = -1; dj <= 1; ++dj) {
      const int Bn = Bc + dj;
      if (Bn < 0 || Bn > 63) continue;
      const int widx = (di + 1) * 3 + (dj + 1);
      const float* vr = v + ((size_t)(b * 4096) + An * 64 + Bn) * 512 + h * 32;
#pragma unroll
      for (int d4 = 0; d4 < 32; d4 += 4) {
        float4 f = *(const float4*)&vr[d4];
        acc[d4]     += wc[(d4)     * 9 + widx] * f.x;
        acc[d4 + 1] += wc[(d4 + 1) * 9 + widx] * f.y;
        acc[d4 + 2] += wc[(d4 + 2) * 9 + widx] * f.z;
        acc[d4 + 3] += wc[(d4 + 3) * 9 + widx] * f.w;
      }
    }
  }

  float* orow = o + qoff;   // o aliases q: own slice fully read above
#pragma unroll
  for (int d4 = 0; d4 < 32; d4 += 4) {
    float4 f;
    f.x = acc[d4]; f.y = acc[d4 + 1]; f.z = acc[d4 + 2]; f.w = acc[d4 + 3];
    *(float4*)&orow[d4] = f;
  }
}

// ---- output projection GEMM, writes final (b,C,64,64) transpose ----------
__global__ __launch_bounds__(256) void proj_gemm(
    const float* __restrict__ o, const float* __restrict__ proj_w,
    const float* __restrict__ proj_b, float* __restrict__ out)
{
  __shared__ float As[16][64];
  __shared__ float Bs[16][64];
  const int tid = threadIdx.x;
  const int tx = tid & 15, ty = tid >> 4;
  const int rowBase = blockIdx.y * 64;
  const int colBase = blockIdx.x * 64;
  const int lr = tid >> 2, lc = (tid & 3) * 4;
  const int br = tid >> 4, bc = (tid & 15) * 4;

  float acc[4][4];
#pragma unroll
  for (int i = 0; i < 4; ++i)
#pragma unroll
    for (int j = 0; j < 4; ++j) acc[i][j] = 0.f;

  for (int k0 = 0; k0 < 512; k0 += 16) {
    float4 a4 = *(const float4*)&o[(size_t)(rowBase + lr) * 512 + k0 + lc];
    As[lc + 0][lr] = a4.x; As[lc + 1][lr] = a4.y;
    As[lc + 2][lr] = a4.z; As[lc + 3][lr] = a4.w;
    *(float4*)&Bs[br][bc] =
        *(const float4*)&proj_w[(size_t)(k0 + br) * 512 + colBase + bc];
    __syncthreads();
#pragma unroll
    for (int kk = 0; kk < 16; ++kk) {
      float4 a = *(const float4*)&As[kk][ty * 4];
      float4 bv = *(const float4*)&Bs[kk][tx * 4];
      acc[0][0] += a.x * bv.x; acc[0][1] += a.x * bv.y;
      acc[0][2] += a.x * bv.z; acc[0][3] += a.x * bv.w;
      acc[1][0] += a.y * bv.x; acc[1][1] += a.y * bv.y;
      acc[1][2] += a.y * bv.z; acc[1][3] += a.y * bv.w;
      acc[2][0] += a.z * bv.x; acc[2][1] += a.z * bv.y;
      acc[2][2] += a.z * bv.z; acc[2][3] += a.z * bv.w;
      acc[3][0] += a.w * bv.x; acc[3][1] += a.w * bv.y;
      acc[3][2] += a.w * bv.z; acc[3][3] += a.w * bv.w;
    }
    __syncthreads();
  }

  const int b = rowBase >> 12;
  const int t0 = (rowBase & 4095) + ty * 4;
#pragma unroll
  for (int j = 0; j < 4; ++j) {
    const int gc = colBase + tx * 4 + j;
    const float pb = proj_b[gc];
    float4 wv;
    wv.x = acc[0][j] + pb; wv.y = acc[1][j] + pb;
    wv.z = acc[2][j] + pb; wv.w = acc[3][j] + pb;
    *(float4*)&out[((size_t)(b * 512 + gc)) * 4096 + t0] = wv;
  }
}

// ---------------------------------------------------------------------------
extern "C" void kernel_launch(void* const* d_in, const int* in_sizes, int n_in,
                              void* d_out, int out_size, void* d_ws, size_t ws_size,
                              hipStream_t stream)
{
  (void)in_sizes; (void)n_in; (void)out_size; (void)ws_size;
  const float* x      = (const float*)d_in[0];
  const float* in_w   = (const float*)d_in[1];
  const float* in_b   = (const float*)d_in[2];
  const float* qkv_w  = (const float*)d_in[3];
  const float* qkv_b  = (const float*)d_in[4];
  const float* proj_w = (const float*)d_in[5];
  const float* proj_b = (const float*)d_in[6];
  const float* dwc_w  = (const float*)d_in[7];
  const float* dwc_b  = (const float*)d_in[8];
  const float* an_b   = (const float*)d_in[9];
  const float* na_b   = (const float*)d_in[10];
  const float* ah_b   = (const float*)d_in[11];
  const float* aw_b   = (const float*)d_in[12];
  const float* ha_b   = (const float*)d_in[13];
  const float* wa_b   = (const float*)d_in[14];
  float* out = (float*)d_out;

  float* q     = (float*)d_ws;               // 33,554,432 f32
  float* kbuf  = q + 33554432ull;            // 33,554,432
  float* vbuf  = kbuf + 33554432ull;         // 33,554,432
  float* qt    = vbuf + 33554432ull;         // 401,408
  float* agv   = qt + 401408ull;             // 401,408
  float* bias1 = agv + 401408ull;            // 3,211,264
  float* bias2 = bias1 + 3211264ull;         // 3,211,264
  float* o     = q;                          // alias (safe: per-thread RAW only)

  qkv_gemm<<<dim3(24, 1024), 256, 0, stream>>>(x, in_w, in_b, qkv_w, qkv_b,
                                               q, kbuf, vbuf);
  pool_qt<<<784, 256, 0, stream>>>(q, qt);
  bias_prep<<<784, 256, 0, stream>>>(an_b, na_b, ah_b, aw_b, ha_b, wa_b,
                                     bias1, bias2);
  stage1<<<12544, 256, 0, stream>>>(qt, kbuf, vbuf, bias1, agv);
  stage2<<<4096, 256, 0, stream>>>(q, vbuf, qt, agv, bias2, dwc_w, dwc_b, o);
  proj_gemm<<<dim3(8, 1024), 256, 0, stream>>>(o, proj_w, proj_b, out);
}

// Round 4
// 3948.660 us; speedup vs baseline: 1.5453x; 1.5453x over previous
//
#include <hip/hip_runtime.h>

// ---------------------------------------------------------------------------
// AgentAttention forward. B=16, CIN=3, H=W=64, n=4096, C=512, NH=16, hd=32,
// AGENT=49. token t = w*64 + h ; grid axes A1 = t>>6, A2 = t&63.
// ---------------------------------------------------------------------------

// ---- qkv GEMM fused with 1x1 input projection -----------------------------
__global__ __launch_bounds__(256) void qkv_gemm(
    const float* __restrict__ x, const float* __restrict__ in_w,
    const float* __restrict__ in_b, const float* __restrict__ qkv_w,
    const float* __restrict__ qkv_b,
    float* __restrict__ q, float* __restrict__ k, float* __restrict__ v)
{
  __shared__ float As[16][64];
  __shared__ float Bs[16][64];
  const int tid = threadIdx.x;
  const int tx = tid & 15, ty = tid >> 4;
  const int rowBase = blockIdx.y * 64;
  const int colBase = blockIdx.x * 64;

  const int lr = tid >> 2;
  const int lc = (tid & 3) * 4;
  const int R  = rowBase + lr;
  const int bb = R >> 12, t = R & 4095;
  const int sp = ((t & 63) << 6) | (t >> 6);
  const float x0 = x[(size_t)(bb * 3 + 0) * 4096 + sp];
  const float x1 = x[(size_t)(bb * 3 + 1) * 4096 + sp];
  const float x2 = x[(size_t)(bb * 3 + 2) * 4096 + sp];

  const int br = tid >> 4;
  const int bc = (tid & 15) * 4;

  float acc[4][4];
#pragma unroll
  for (int i = 0; i < 4; ++i)
#pragma unroll
    for (int j = 0; j < 4; ++j) acc[i][j] = 0.f;

  for (int k0 = 0; k0 < 512; k0 += 16) {
    const int kb = k0 + lc;
    float4 w0 = *(const float4*)&in_w[kb];
    float4 w1 = *(const float4*)&in_w[512 + kb];
    float4 w2 = *(const float4*)&in_w[1024 + kb];
    float4 b4 = *(const float4*)&in_b[kb];
    As[lc + 0][lr] = b4.x + x0 * w0.x + x1 * w1.x + x2 * w2.x;
    As[lc + 1][lr] = b4.y + x0 * w0.y + x1 * w1.y + x2 * w2.y;
    As[lc + 2][lr] = b4.z + x0 * w0.z + x1 * w1.z + x2 * w2.z;
    As[lc + 3][lr] = b4.w + x0 * w0.w + x1 * w1.w + x2 * w2.w;
    *(float4*)&Bs[br][bc] =
        *(const float4*)&qkv_w[(size_t)(k0 + br) * 1536 + colBase + bc];
    __syncthreads();
#pragma unroll
    for (int kk = 0; kk < 16; ++kk) {
      float4 a4 = *(const float4*)&As[kk][ty * 4];
      float4 bv = *(const float4*)&Bs[kk][tx * 4];
      acc[0][0] += a4.x * bv.x; acc[0][1] += a4.x * bv.y;
      acc[0][2] += a4.x * bv.z; acc[0][3] += a4.x * bv.w;
      acc[1][0] += a4.y * bv.x; acc[1][1] += a4.y * bv.y;
      acc[1][2] += a4.y * bv.z; acc[1][3] += a4.y * bv.w;
      acc[2][0] += a4.z * bv.x; acc[2][1] += a4.z * bv.y;
      acc[2][2] += a4.z * bv.z; acc[2][3] += a4.z * bv.w;
      acc[3][0] += a4.w * bv.x; acc[3][1] += a4.w * bv.y;
      acc[3][2] += a4.w * bv.z; acc[3][3] += a4.w * bv.w;
    }
    __syncthreads();
  }

  const int gc0 = colBase + tx * 4;
  float* dst; int lc0;
  if (gc0 < 512)       { dst = q; lc0 = gc0; }
  else if (gc0 < 1024) { dst = k; lc0 = gc0 - 512; }
  else                 { dst = v; lc0 = gc0 - 1024; }
  float4 bias = *(const float4*)&qkv_b[gc0];
#pragma unroll
  for (int i = 0; i < 4; ++i) {
    const int Rw = rowBase + ty * 4 + i;
    float4 wv;
    wv.x = acc[i][0] + bias.x; wv.y = acc[i][1] + bias.y;
    wv.z = acc[i][2] + bias.z; wv.w = acc[i][3] + bias.w;
    *(float4*)&dst[(size_t)Rw * 512 + lc0] = wv;
  }
}

// ---- adaptive avg pool q -> qt (b,49,512) ---------------------------------
__global__ __launch_bounds__(256) void pool_qt(const float* __restrict__ q,
                                               float* __restrict__ qt)
{
  const int blk = blockIdx.x;
  const int a = blk % 49, b = blk / 49;
  const int iA = a / 7, iB = a % 7;
  const int sA = (iA * 64) / 7, eA = ((iA + 1) * 64 + 6) / 7;
  const int sB = (iB * 64) / 7, eB = ((iB + 1) * 64 + 6) / 7;
  const float invn = 1.0f / (float)((eA - sA) * (eB - sB));
  for (int c = threadIdx.x; c < 512; c += 256) {
    float s = 0.f;
    for (int A = sA; A < eA; ++A)
      for (int Bb = sB; Bb < eB; ++Bb)
        s += q[((size_t)b * 4096 + A * 64 + Bb) * 512 + c];
    qt[((size_t)b * 49 + a) * 512 + c] = s * invn;
  }
}

// ---- bias precompute ------------------------------------------------------
// bias1 [h][a][t] ; bias2t [h][a][t]  (stage2 reads transposed for coalescing)
__global__ __launch_bounds__(256) void bias_prep(
    const float* __restrict__ an, const float* __restrict__ na,
    const float* __restrict__ ah, const float* __restrict__ aw,
    const float* __restrict__ ha, const float* __restrict__ wa,
    float* __restrict__ bias1, float* __restrict__ bias2t)
{
  const int blk = blockIdx.x;
  const int a = blk % 49, h = blk / 49;
  const float* anp = an + (size_t)(h * 49 + a) * 49;
  const float* nap = na + (size_t)(h * 49 + a) * 49;
  for (int t = threadIdx.x; t < 4096; t += 256) {
    const int tA = t >> 6, tB = t & 63;
    float cA = (tA + 0.5f) * 0.109375f - 0.5f;
    cA = fminf(fmaxf(cA, 0.f), 6.f);
    int i0A = (int)floorf(cA); float wA = cA - (float)i0A;
    int i1A = min(i0A + 1, 6);
    float cB = (tB + 0.5f) * 0.109375f - 0.5f;
    cB = fminf(fmaxf(cB, 0.f), 6.f);
    int i0B = (int)floorf(cB); float wB = cB - (float)i0B;
    int i1B = min(i0B + 1, 6);

    float v1 = (1.f - wA) * ((1.f - wB) * anp[i0A * 7 + i0B] + wB * anp[i0A * 7 + i1B]) +
               wA        * ((1.f - wB) * anp[i1A * 7 + i0B] + wB * anp[i1A * 7 + i1B]);
    float v2 = (1.f - wA) * ((1.f - wB) * nap[i0A * 7 + i0B] + wB * nap[i0A * 7 + i1B]) +
               wA        * ((1.f - wB) * nap[i1A * 7 + i0B] + wB * nap[i1A * 7 + i1B]);

    bias1[((size_t)h * 49 + a) * 4096 + t] =
        v1 + ah[(size_t)(h * 49 + a) * 64 + tA] + aw[(size_t)(h * 49 + a) * 64 + tB];
    bias2t[((size_t)h * 49 + a) * 4096 + t] =
        v2 + ha[((size_t)h * 64 + tA) * 49 + a] + wa[((size_t)h * 64 + tB) * 49 + a];
  }
}

// ---- stage 1: agent->token attention, one block per (b,h) -----------------
// K/V tiled 128 tokens into LDS; online softmax over 49 agents; flash-style.
__global__ __launch_bounds__(256) void stage1(
    const float* __restrict__ qt, const float* __restrict__ k,
    const float* __restrict__ v, const float* __restrict__ bias1,
    float* __restrict__ agent_v)
{
  __shared__ float Kt[128][36];     // padded: conflict-free b128
  __shared__ float Vt[128][36];
  __shared__ float S[49][132];      // P tile, 16B-aligned row stride
  __shared__ float m_s[64], l_s[64], corr_s[64];
  __shared__ float red[49][4];

  const int bh = blockIdx.x;
  const int h = bh & 15, b = bh >> 4;
  const int tid = threadIdx.x;
  const int w = tid >> 6, lane = tid & 63;
  const float scale = 0.17677669529663689f;

  // qt row for agent = lane, held in registers (per wave, redundant copies)
  float qs[32];
  if (lane < 49) {
    const float* qp = qt + ((size_t)b * 49 + lane) * 512 + h * 32;
#pragma unroll
    for (int d4 = 0; d4 < 8; ++d4) {
      float4 f = *(const float4*)&qp[d4 * 4];
      qs[d4 * 4 + 0] = f.x * scale; qs[d4 * 4 + 1] = f.y * scale;
      qs[d4 * 4 + 2] = f.z * scale; qs[d4 * 4 + 3] = f.w * scale;
    }
  } else {
#pragma unroll
    for (int d = 0; d < 32; ++d) qs[d] = 0.f;
  }
  if (tid < 64) { m_s[tid] = -3.0e38f; l_s[tid] = 0.f; corr_s[tid] = 1.f; }

  // PV slots: slot1 = tid -> (a1 = tid>>3, d41 = tid&7); slot2 = 256+tid (tid<136)
  const int a1 = tid >> 3, d41 = tid & 7;
  const int s2 = 256 + tid;
  const int a2 = s2 >> 3, d42 = s2 & 7;
  const bool has2 = (tid < 136);
  float4 acc1 = {0.f, 0.f, 0.f, 0.f};
  float4 acc2 = {0.f, 0.f, 0.f, 0.f};

  const float* kbase = k + (size_t)b * 4096 * 512 + h * 32;
  const float* vbase = v + (size_t)b * 4096 * 512 + h * 32;
  const float* b1h   = bias1 + (size_t)h * 49 * 4096;

  for (int tile = 0; tile < 32; ++tile) {
    __syncthreads();   // prev PV / l-update done before overwriting LDS
    // ---- load K/V tile: 128 tokens x 32 floats each -----------------------
#pragma unroll
    for (int i = 0; i < 4; ++i) {
      int idx = tid + i * 256;               // 0..1023
      int r = idx >> 3, d4 = idx & 7;
      size_t go = (size_t)(tile * 128 + r) * 512 + d4 * 4;
      *(float4*)&Kt[r][d4 * 4] = *(const float4*)&kbase[go];
      *(float4*)&Vt[r][d4 * 4] = *(const float4*)&vbase[go];
    }
    __syncthreads();

    // ---- scores: wave w computes tokens w*32..+31 for agent = lane --------
    float sv[32];
    if (lane < 49) {
      const float* brow = b1h + (size_t)lane * 4096 + tile * 128 + w * 32;
#pragma unroll
      for (int i4 = 0; i4 < 8; ++i4) {       // init with bias (issues loads early)
        float4 bi = *(const float4*)&brow[i4 * 4];
        sv[i4 * 4 + 0] = bi.x; sv[i4 * 4 + 1] = bi.y;
        sv[i4 * 4 + 2] = bi.z; sv[i4 * 4 + 3] = bi.w;
      }
#pragma unroll
      for (int i = 0; i < 32; ++i) {
        const int tt = w * 32 + i;
        float s = 0.f;
#pragma unroll
        for (int d4 = 0; d4 < 8; ++d4) {
          float4 kf = *(const float4*)&Kt[tt][d4 * 4];   // wave-broadcast
          s += qs[d4 * 4] * kf.x + qs[d4 * 4 + 1] * kf.y +
               qs[d4 * 4 + 2] * kf.z + qs[d4 * 4 + 3] * kf.w;
        }
        sv[i] += s;
      }
      float mx = -3.0e38f;
#pragma unroll
      for (int i = 0; i < 32; ++i) mx = fmaxf(mx, sv[i]);
      red[lane][w] = mx;
    }
    __syncthreads();

    if (tid < 49) {
      float mo = m_s[tid];
      float mx = fmaxf(fmaxf(red[tid][0], red[tid][1]),
                       fmaxf(red[tid][2], red[tid][3]));
      mx = fmaxf(mx, mo);
      float c = __expf(mo - mx);
      m_s[tid] = mx; corr_s[tid] = c; l_s[tid] *= c;
    }
    __syncthreads();

    // ---- exp + write P + partial sum --------------------------------------
    if (lane < 49) {
      const float m = m_s[lane];
      float sm = 0.f;
#pragma unroll
      for (int i = 0; i < 32; ++i) {
        float p = __expf(sv[i] - m);
        sm += p;
        S[lane][w * 32 + i] = p;
      }
      red[lane][w] = sm;
    }
    __syncthreads();

    if (tid < 49)
      l_s[tid] += red[tid][0] + red[tid][1] + red[tid][2] + red[tid][3];

    // ---- PV: acc[a][d4*4..+3] += P[a][tt] * V[tt][d] ----------------------
    {
      const float c1 = corr_s[a1];
      acc1.x *= c1; acc1.y *= c1; acc1.z *= c1; acc1.w *= c1;
#pragma unroll
      for (int tt4 = 0; tt4 < 32; ++tt4) {
        float4 p = *(const float4*)&S[a1][tt4 * 4];
        float4 v0 = *(const float4*)&Vt[tt4 * 4 + 0][d41 * 4];
        float4 v1 = *(const float4*)&Vt[tt4 * 4 + 1][d41 * 4];
        float4 v2 = *(const float4*)&Vt[tt4 * 4 + 2][d41 * 4];
        float4 v3 = *(const float4*)&Vt[tt4 * 4 + 3][d41 * 4];
        acc1.x += p.x * v0.x + p.y * v1.x + p.z * v2.x + p.w * v3.x;
        acc1.y += p.x * v0.y + p.y * v1.y + p.z * v2.y + p.w * v3.y;
        acc1.z += p.x * v0.z + p.y * v1.z + p.z * v2.z + p.w * v3.z;
        acc1.w += p.x * v0.w + p.y * v1.w + p.z * v2.w + p.w * v3.w;
      }
    }
    if (has2) {
      const float c2 = corr_s[a2];
      acc2.x *= c2; acc2.y *= c2; acc2.z *= c2; acc2.w *= c2;
#pragma unroll
      for (int tt4 = 0; tt4 < 32; ++tt4) {
        float4 p = *(const float4*)&S[a2][tt4 * 4];
        float4 v0 = *(const float4*)&Vt[tt4 * 4 + 0][d42 * 4];
        float4 v1 = *(const float4*)&Vt[tt4 * 4 + 1][d42 * 4];
        float4 v2 = *(const float4*)&Vt[tt4 * 4 + 2][d42 * 4];
        float4 v3 = *(const float4*)&Vt[tt4 * 4 + 3][d42 * 4];
        acc2.x += p.x * v0.x + p.y * v1.x + p.z * v2.x + p.w * v3.x;
        acc2.y += p.x * v0.y + p.y * v1.y + p.z * v2.y + p.w * v3.y;
        acc2.z += p.x * v0.z + p.y * v1.z + p.z * v2.z + p.w * v3.z;
        acc2.w += p.x * v0.w + p.y * v1.w + p.z * v2.w + p.w * v3.w;
      }
    }
  }
  __syncthreads();

  {
    const float inv = 1.0f / l_s[a1];
    float4 o; o.x = acc1.x * inv; o.y = acc1.y * inv;
    o.z = acc1.z * inv; o.w = acc1.w * inv;
    *(float4*)&agent_v[(((size_t)b * 16 + h) * 49 + a1) * 32 + d41 * 4] = o;
  }
  if (has2) {
    const float inv = 1.0f / l_s[a2];
    float4 o; o.x = acc2.x * inv; o.y = acc2.y * inv;
    o.z = acc2.z * inv; o.w = acc2.w * inv;
    *(float4*)&agent_v[(((size_t)b * 16 + h) * 49 + a2) * 32 + d42 * 4] = o;
  }
}

// ---- stage 2: token->agent attention + dwc 3x3 + residual -----------------
// one block per (b,h,256-token tile); scores in registers; LDS broadcasts.
__global__ __launch_bounds__(256) void stage2(
    const float* __restrict__ q, const float* __restrict__ v,
    const float* __restrict__ qt, const float* __restrict__ agent_v,
    const float* __restrict__ bias2t, const float* __restrict__ dwc_w,
    const float* __restrict__ dwc_b, float* __restrict__ o)
{
  __shared__ float qts[49][32];
  __shared__ float avs[49][32];
  __shared__ float wcs[9][32];
  __shared__ float wb[32];

  const int tid = threadIdx.x;
  const int blk = blockIdx.x;
  const int b = blk >> 8, h = (blk >> 4) & 15, tg = blk & 15;
  const int t = tg * 256 + tid;
  const float scale = 0.17677669529663689f;

  // ---- stage LDS ----------------------------------------------------------
  if (tid < 196) {  // 392 float4 slots, 2 per thread
#pragma unroll
    for (int rep = 0; rep < 2; ++rep) {
      int idx = tid + rep * 196;
      int a = idx >> 3, d4 = idx & 7;
      *(float4*)&qts[a][d4 * 4] =
          *(const float4*)&qt[((size_t)b * 49 + a) * 512 + h * 32 + d4 * 4];
      *(float4*)&avs[a][d4 * 4] =
          *(const float4*)&agent_v[(((size_t)b * 16 + h) * 49 + a) * 32 + d4 * 4];
    }
  }
  for (int idx = tid; idx < 288; idx += 256) {   // FIX: 288 slots > 256 threads
    int j = idx >> 5, d = idx & 31;
    wcs[j][d] = dwc_w[(size_t)(h * 32 + d) * 9 + j];
  }
  if (tid < 32) wb[tid] = dwc_b[h * 32 + tid];
  __syncthreads();

  // ---- q row in regs ------------------------------------------------------
  const size_t qoff = ((size_t)(b * 4096 + t)) * 512 + h * 32;
  float qr[32];
#pragma unroll
  for (int d4 = 0; d4 < 8; ++d4) {
    float4 f = *(const float4*)&q[qoff + d4 * 4];
    qr[d4 * 4 + 0] = f.x * scale; qr[d4 * 4 + 1] = f.y * scale;
    qr[d4 * 4 + 2] = f.z * scale; qr[d4 * 4 + 3] = f.w * scale;
  }

  // ---- scores (bias loads issue first; coalesced across lanes) ------------
  float s[49];
  const float* b2 = bias2t + (size_t)h * 49 * 4096 + t;
#pragma unroll
  for (int a = 0; a < 49; ++a) s[a] = b2[(size_t)a * 4096];
#pragma unroll
  for (int a = 0; a < 49; ++a) {
    float acc = 0.f;
#pragma unroll
    for (int d4 = 0; d4 < 8; ++d4) {
      float4 f = *(const float4*)&qts[a][d4 * 4];      // broadcast
      acc += qr[d4 * 4] * f.x + qr[d4 * 4 + 1] * f.y +
             qr[d4 * 4 + 2] * f.z + qr[d4 * 4 + 3] * f.w;
    }
    s[a] += acc;
  }

  // ---- softmax in registers ----------------------------------------------
  float m = -3.0e38f;
#pragma unroll
  for (int a = 0; a < 49; ++a) m = fmaxf(m, s[a]);
  float S = 0.f;
#pragma unroll
  for (int a = 0; a < 49; ++a) { s[a] = __expf(s[a] - m); S += s[a]; }
  const float inv = 1.0f / S;

  // ---- PV + dwc bias ------------------------------------------------------
  float acc[32];
#pragma unroll
  for (int d = 0; d < 32; ++d) acc[d] = wb[d];
#pragma unroll
  for (int a = 0; a < 49; ++a) {
    const float pn = s[a] * inv;
#pragma unroll
    for (int d4 = 0; d4 < 8; ++d4) {
      float4 f = *(const float4*)&avs[a][d4 * 4];      // broadcast
      acc[d4 * 4 + 0] += pn * f.x; acc[d4 * 4 + 1] += pn * f.y;
      acc[d4 * 4 + 2] += pn * f.z; acc[d4 * 4 + 3] += pn * f.w;
    }
  }

  // ---- depthwise 3x3 conv on v -------------------------------------------
  const int A = t >> 6, Bc = t & 63;
#pragma unroll
  for (int widx = 0; widx < 9; ++widx) {
    const int di = widx / 3 - 1, dj = widx % 3 - 1;
    const int An = A + di, Bn = Bc + dj;
    if (An < 0 || An > 63 || Bn < 0 || Bn > 63) continue;
    const float* vr = v + ((size_t)(b * 4096) + An * 64 + Bn) * 512 + h * 32;
#pragma unroll
    for (int d4 = 0; d4 < 8; ++d4) {
      float4 f = *(const float4*)&vr[d4 * 4];
      float4 wf = *(const float4*)&wcs[widx][d4 * 4];  // broadcast
      acc[d4 * 4 + 0] += wf.x * f.x; acc[d4 * 4 + 1] += wf.y * f.y;
      acc[d4 * 4 + 2] += wf.z * f.z; acc[d4 * 4 + 3] += wf.w * f.w;
    }
  }

  float* orow = o + qoff;     // o aliases q: own slice fully read above
#pragma unroll
  for (int d4 = 0; d4 < 8; ++d4) {
    float4 f;
    f.x = acc[d4 * 4]; f.y = acc[d4 * 4 + 1];
    f.z = acc[d4 * 4 + 2]; f.w = acc[d4 * 4 + 3];
    *(float4*)&orow[d4 * 4] = f;
  }
}

// ---- output projection GEMM, writes final (b,C,64,64) transpose ----------
__global__ __launch_bounds__(256) void proj_gemm(
    const float* __restrict__ o, const float* __restrict__ proj_w,
    const float* __restrict__ proj_b, float* __restrict__ out)
{
  __shared__ float As[16][64];
  __shared__ float Bs[16][64];
  const int tid = threadIdx.x;
  const int tx = tid & 15, ty = tid >> 4;
  const int rowBase = blockIdx.y * 64;
  const int colBase = blockIdx.x * 64;
  const int lr = tid >> 2, lc = (tid & 3) * 4;
  const int br = tid >> 4, bc = (tid & 15) * 4;

  float acc[4][4];
#pragma unroll
  for (int i = 0; i < 4; ++i)
#pragma unroll
    for (int j = 0; j < 4; ++j) acc[i][j] = 0.f;

  for (int k0 = 0; k0 < 512; k0 += 16) {
    float4 a4 = *(const float4*)&o[(size_t)(rowBase + lr) * 512 + k0 + lc];
    As[lc + 0][lr] = a4.x; As[lc + 1][lr] = a4.y;
    As[lc + 2][lr] = a4.z; As[lc + 3][lr] = a4.w;
    *(float4*)&Bs[br][bc] =
        *(const float4*)&proj_w[(size_t)(k0 + br) * 512 + colBase + bc];
    __syncthreads();
#pragma unroll
    for (int kk = 0; kk < 16; ++kk) {
      float4 a = *(const float4*)&As[kk][ty * 4];
      float4 bv = *(const float4*)&Bs[kk][tx * 4];
      acc[0][0] += a.x * bv.x; acc[0][1] += a.x * bv.y;
      acc[0][2] += a.x * bv.z; acc[0][3] += a.x * bv.w;
      acc[1][0] += a.y * bv.x; acc[1][1] += a.y * bv.y;
      acc[1][2] += a.y * bv.z; acc[1][3] += a.y * bv.w;
      acc[2][0] += a.z * bv.x; acc[2][1] += a.z * bv.y;
      acc[2][2] += a.z * bv.z; acc[2][3] += a.z * bv.w;
      acc[3][0] += a.w * bv.x; acc[3][1] += a.w * bv.y;
      acc[3][2] += a.w * bv.z; acc[3][3] += a.w * bv.w;
    }
    __syncthreads();
  }

  const int b = rowBase >> 12;
  const int t0 = (rowBase & 4095) + ty * 4;
#pragma unroll
  for (int j = 0; j < 4; ++j) {
    const int gc = colBase + tx * 4 + j;
    const float pb = proj_b[gc];
    float4 wv;
    wv.x = acc[0][j] + pb; wv.y = acc[1][j] + pb;
    wv.z = acc[2][j] + pb; wv.w = acc[3][j] + pb;
    *(float4*)&out[((size_t)(b * 512 + gc)) * 4096 + t0] = wv;
  }
}

// ---------------------------------------------------------------------------
extern "C" void kernel_launch(void* const* d_in, const int* in_sizes, int n_in,
                              void* d_out, int out_size, void* d_ws, size_t ws_size,
                              hipStream_t stream)
{
  (void)in_sizes; (void)n_in; (void)out_size; (void)ws_size;
  const float* x      = (const float*)d_in[0];
  const float* in_w   = (const float*)d_in[1];
  const float* in_b   = (const float*)d_in[2];
  const float* qkv_w  = (const float*)d_in[3];
  const float* qkv_b  = (const float*)d_in[4];
  const float* proj_w = (const float*)d_in[5];
  const float* proj_b = (const float*)d_in[6];
  const float* dwc_w  = (const float*)d_in[7];
  const float* dwc_b  = (const float*)d_in[8];
  const float* an_b   = (const float*)d_in[9];
  const float* na_b   = (const float*)d_in[10];
  const float* ah_b   = (const float*)d_in[11];
  const float* aw_b   = (const float*)d_in[12];
  const float* ha_b   = (const float*)d_in[13];
  const float* wa_b   = (const float*)d_in[14];
  float* out = (float*)d_out;

  float* q     = (float*)d_ws;               // 33,554,432 f32
  float* kbuf  = q + 33554432ull;            // 33,554,432
  float* vbuf  = kbuf + 33554432ull;         // 33,554,432
  float* qt    = vbuf + 33554432ull;         // 401,408
  float* agv   = qt + 401408ull;             // 401,408
  float* bias1 = agv + 401408ull;            // 3,211,264
  float* bias2t= bias1 + 3211264ull;         // 3,211,264
  float* o     = q;                          // alias (per-thread RAW only)

  qkv_gemm<<<dim3(24, 1024), 256, 0, stream>>>(x, in_w, in_b, qkv_w, qkv_b,
                                               q, kbuf, vbuf);
  pool_qt<<<784, 256, 0, stream>>>(q, qt);
  bias_prep<<<784, 256, 0, stream>>>(an_b, na_b, ah_b, aw_b, ha_b, wa_b,
                                     bias1, bias2t);
  stage1<<<256, 256, 0, stream>>>(qt, kbuf, vbuf, bias1, agv);
  stage2<<<4096, 256, 0, stream>>>(q, vbuf, qt, agv, bias2t, dwc_w, dwc_b, o);
  proj_gemm<<<dim3(8, 1024), 256, 0, stream>>>(o, proj_w, proj_b, out);
}

// Round 5
// 2827.658 us; speedup vs baseline: 2.1579x; 1.3964x over previous
//
#include <hip/hip_runtime.h>

// ---------------------------------------------------------------------------
// AgentAttention forward. B=16, CIN=3, H=W=64, n=4096, C=512, NH=16, hd=32,
// AGENT=49. token t = w*64 + h ; grid axes A1 = t>>6, A2 = t&63.
// ---------------------------------------------------------------------------

// ---- qkv GEMM fused with 1x1 input projection -----------------------------
__global__ __launch_bounds__(256) void qkv_gemm(
    const float* __restrict__ x, const float* __restrict__ in_w,
    const float* __restrict__ in_b, const float* __restrict__ qkv_w,
    const float* __restrict__ qkv_b,
    float* __restrict__ q, float* __restrict__ k, float* __restrict__ v)
{
  __shared__ float As[16][64];
  __shared__ float Bs[16][64];
  const int tid = threadIdx.x;
  const int tx = tid & 15, ty = tid >> 4;
  const int rowBase = blockIdx.y * 64;
  const int colBase = blockIdx.x * 64;

  const int lr = tid >> 2;
  const int lc = (tid & 3) * 4;
  const int R  = rowBase + lr;
  const int bb = R >> 12, t = R & 4095;
  const int sp = ((t & 63) << 6) | (t >> 6);
  const float x0 = x[(size_t)(bb * 3 + 0) * 4096 + sp];
  const float x1 = x[(size_t)(bb * 3 + 1) * 4096 + sp];
  const float x2 = x[(size_t)(bb * 3 + 2) * 4096 + sp];

  const int br = tid >> 4;
  const int bc = (tid & 15) * 4;

  float acc[4][4];
#pragma unroll
  for (int i = 0; i < 4; ++i)
#pragma unroll
    for (int j = 0; j < 4; ++j) acc[i][j] = 0.f;

  for (int k0 = 0; k0 < 512; k0 += 16) {
    const int kb = k0 + lc;
    float4 w0 = *(const float4*)&in_w[kb];
    float4 w1 = *(const float4*)&in_w[512 + kb];
    float4 w2 = *(const float4*)&in_w[1024 + kb];
    float4 b4 = *(const float4*)&in_b[kb];
    As[lc + 0][lr] = b4.x + x0 * w0.x + x1 * w1.x + x2 * w2.x;
    As[lc + 1][lr] = b4.y + x0 * w0.y + x1 * w1.y + x2 * w2.y;
    As[lc + 2][lr] = b4.z + x0 * w0.z + x1 * w1.z + x2 * w2.z;
    As[lc + 3][lr] = b4.w + x0 * w0.w + x1 * w1.w + x2 * w2.w;
    *(float4*)&Bs[br][bc] =
        *(const float4*)&qkv_w[(size_t)(k0 + br) * 1536 + colBase + bc];
    __syncthreads();
#pragma unroll
    for (int kk = 0; kk < 16; ++kk) {
      float4 a4 = *(const float4*)&As[kk][ty * 4];
      float4 bv = *(const float4*)&Bs[kk][tx * 4];
      acc[0][0] += a4.x * bv.x; acc[0][1] += a4.x * bv.y;
      acc[0][2] += a4.x * bv.z; acc[0][3] += a4.x * bv.w;
      acc[1][0] += a4.y * bv.x; acc[1][1] += a4.y * bv.y;
      acc[1][2] += a4.y * bv.z; acc[1][3] += a4.y * bv.w;
      acc[2][0] += a4.z * bv.x; acc[2][1] += a4.z * bv.y;
      acc[2][2] += a4.z * bv.z; acc[2][3] += a4.z * bv.w;
      acc[3][0] += a4.w * bv.x; acc[3][1] += a4.w * bv.y;
      acc[3][2] += a4.w * bv.z; acc[3][3] += a4.w * bv.w;
    }
    __syncthreads();
  }

  const int gc0 = colBase + tx * 4;
  float* dst; int lc0;
  if (gc0 < 512)       { dst = q; lc0 = gc0; }
  else if (gc0 < 1024) { dst = k; lc0 = gc0 - 512; }
  else                 { dst = v; lc0 = gc0 - 1024; }
  float4 bias = *(const float4*)&qkv_b[gc0];
#pragma unroll
  for (int i = 0; i < 4; ++i) {
    const int Rw = rowBase + ty * 4 + i;
    float4 wv;
    wv.x = acc[i][0] + bias.x; wv.y = acc[i][1] + bias.y;
    wv.z = acc[i][2] + bias.z; wv.w = acc[i][3] + bias.w;
    *(float4*)&dst[(size_t)Rw * 512 + lc0] = wv;
  }
}

// ---- adaptive avg pool q -> qt (b,49,512) ---------------------------------
__global__ __launch_bounds__(256) void pool_qt(const float* __restrict__ q,
                                               float* __restrict__ qt)
{
  const int blk = blockIdx.x;
  const int a = blk % 49, b = blk / 49;
  const int iA = a / 7, iB = a % 7;
  const int sA = (iA * 64) / 7, eA = ((iA + 1) * 64 + 6) / 7;
  const int sB = (iB * 64) / 7, eB = ((iB + 1) * 64 + 6) / 7;
  const float invn = 1.0f / (float)((eA - sA) * (eB - sB));
  for (int c = threadIdx.x; c < 512; c += 256) {
    float s = 0.f;
    for (int A = sA; A < eA; ++A)
      for (int Bb = sB; Bb < eB; ++Bb)
        s += q[((size_t)b * 4096 + A * 64 + Bb) * 512 + c];
    qt[((size_t)b * 49 + a) * 512 + c] = s * invn;
  }
}

// ---- bias precompute ------------------------------------------------------
// bias1 [h][a][t] ; bias2t [h][a][t]  (stage2 reads transposed for coalescing)
__global__ __launch_bounds__(256) void bias_prep(
    const float* __restrict__ an, const float* __restrict__ na,
    const float* __restrict__ ah, const float* __restrict__ aw,
    const float* __restrict__ ha, const float* __restrict__ wa,
    float* __restrict__ bias1, float* __restrict__ bias2t)
{
  const int blk = blockIdx.x;
  const int a = blk % 49, h = blk / 49;
  const float* anp = an + (size_t)(h * 49 + a) * 49;
  const float* nap = na + (size_t)(h * 49 + a) * 49;
  for (int t = threadIdx.x; t < 4096; t += 256) {
    const int tA = t >> 6, tB = t & 63;
    float cA = (tA + 0.5f) * 0.109375f - 0.5f;
    cA = fminf(fmaxf(cA, 0.f), 6.f);
    int i0A = (int)floorf(cA); float wA = cA - (float)i0A;
    int i1A = min(i0A + 1, 6);
    float cB = (tB + 0.5f) * 0.109375f - 0.5f;
    cB = fminf(fmaxf(cB, 0.f), 6.f);
    int i0B = (int)floorf(cB); float wB = cB - (float)i0B;
    int i1B = min(i0B + 1, 6);

    float v1 = (1.f - wA) * ((1.f - wB) * anp[i0A * 7 + i0B] + wB * anp[i0A * 7 + i1B]) +
               wA        * ((1.f - wB) * anp[i1A * 7 + i0B] + wB * anp[i1A * 7 + i1B]);
    float v2 = (1.f - wA) * ((1.f - wB) * nap[i0A * 7 + i0B] + wB * nap[i0A * 7 + i1B]) +
               wA        * ((1.f - wB) * nap[i1A * 7 + i0B] + wB * nap[i1A * 7 + i1B]);

    bias1[((size_t)h * 49 + a) * 4096 + t] =
        v1 + ah[(size_t)(h * 49 + a) * 64 + tA] + aw[(size_t)(h * 49 + a) * 64 + tB];
    bias2t[((size_t)h * 49 + a) * 4096 + t] =
        v2 + ha[((size_t)h * 64 + tA) * 49 + a] + wa[((size_t)h * 64 + tB) * 49 + a];
  }
}

// ---- stage 1a: split-K flash partials. grid = (b,h,chunk16) = 4096 --------
// Per block: 256-token chunk, 4 sub-tiles of 64 tokens, online softmax over
// 49 agents. Scores live in LDS (bias -> scores -> P in place); no reg arrays.
__global__ __launch_bounds__(256) void s1_partial(
    const float* __restrict__ qt, const float* __restrict__ k,
    const float* __restrict__ v, const float* __restrict__ bias1,
    float* __restrict__ pacc, float* __restrict__ pm, float* __restrict__ pl)
{
  __shared__ float qts[49][32];     //  6272 B
  __shared__ float Kt[64][36];      //  9216 B
  __shared__ float Vt[64][36];      //  9216 B
  __shared__ float Sb[49][68];      // 13328 B  (bias -> scores -> P)
  __shared__ float m_s[56], l_s[56], corr_s[56];
  __shared__ float red[49][4];      // total ~39.5 KB -> 4 blocks/CU

  const int blk = blockIdx.x;
  const int c  = blk & 15;
  const int bh = blk >> 4;
  const int h = bh & 15, b = bh >> 4;
  const int tid = threadIdx.x;
  const float scale = 0.17677669529663689f;

  if (tid < 196) {
#pragma unroll
    for (int rep = 0; rep < 2; ++rep) {
      int idx = tid + rep * 196;
      int aa = idx >> 3, d4 = idx & 7;
      float4 f = *(const float4*)&qt[((size_t)b * 49 + aa) * 512 + h * 32 + d4 * 4];
      f.x *= scale; f.y *= scale; f.z *= scale; f.w *= scale;
      *(float4*)&qts[aa][d4 * 4] = f;
    }
  }
  if (tid < 56) { m_s[tid] = -3.0e38f; l_s[tid] = 0.f; corr_s[tid] = 1.f; }
  __syncthreads();

  // score-phase mapping: thread -> (agent a, token-quarter tq), t = tq + 4i
  const int a  = tid >> 2, tq = tid & 3;     // valid for tid<196
  float qsr[32];
  if (tid < 196) {
#pragma unroll
    for (int d4 = 0; d4 < 8; ++d4) {
      float4 f = *(const float4*)&qts[a][d4 * 4];
      qsr[d4 * 4 + 0] = f.x; qsr[d4 * 4 + 1] = f.y;
      qsr[d4 * 4 + 2] = f.z; qsr[d4 * 4 + 3] = f.w;
    }
  }

  // PV slots: slot1 = tid -> (a1,d41); slot2 = 256+tid for tid<136
  const int a1 = tid >> 3, d41 = tid & 7;
  const int a2 = 32 + (tid >> 3), d42 = tid & 7;
  const bool has2 = (tid < 136);
  float4 acc1 = {0.f, 0.f, 0.f, 0.f};
  float4 acc2 = {0.f, 0.f, 0.f, 0.f};

  const float* kbase = k + (size_t)b * 4096 * 512 + h * 32;
  const float* vbase = v + (size_t)b * 4096 * 512 + h * 32;
  const float* bbase = bias1 + (size_t)(h * 49) * 4096 + c * 256;

  for (int st = 0; st < 4; ++st) {
    const int t0 = st * 64;
    // ---- stage K/V sub-tile + bias slab ----------------------------------
#pragma unroll
    for (int i = 0; i < 2; ++i) {
      int idx = tid + i * 256;
      int r = idx >> 3, d4 = idx & 7;
      size_t go = (size_t)(c * 256 + t0 + r) * 512 + d4 * 4;
      *(float4*)&Kt[r][d4 * 4] = *(const float4*)&kbase[go];
      *(float4*)&Vt[r][d4 * 4] = *(const float4*)&vbase[go];
    }
    for (int idx = tid; idx < 784; idx += 256) {   // 49 x 16 float4
      int aa = idx >> 4, d16 = idx & 15;
      *(float4*)&Sb[aa][d16 * 4] =
          *(const float4*)&bbase[(size_t)aa * 4096 + t0 + d16 * 4];
    }
    __syncthreads();

    // ---- scores into Sb (in place over bias) -----------------------------
    if (tid < 196) {
      float mloc = -3.0e38f;
#pragma unroll
      for (int i = 0; i < 16; ++i) {
        const int t = tq + i * 4;
        float s = Sb[a][t];
#pragma unroll
        for (int d4 = 0; d4 < 8; ++d4) {
          float4 kf = *(const float4*)&Kt[t][d4 * 4];
          s += qsr[d4 * 4] * kf.x + qsr[d4 * 4 + 1] * kf.y +
               qsr[d4 * 4 + 2] * kf.z + qsr[d4 * 4 + 3] * kf.w;
        }
        Sb[a][t] = s;
        mloc = fmaxf(mloc, s);
      }
      red[a][tq] = mloc;
    }
    __syncthreads();

    if (tid < 49) {
      float mo = m_s[tid];
      float mx = fmaxf(fmaxf(red[tid][0], red[tid][1]),
                       fmaxf(red[tid][2], red[tid][3]));
      mx = fmaxf(mx, mo);
      float cc = __expf(mo - mx);
      m_s[tid] = mx; corr_s[tid] = cc; l_s[tid] *= cc;
    }
    __syncthreads();

    // ---- exp in place + partial sums -------------------------------------
    if (tid < 196) {
      const float m = m_s[a];
      float sm = 0.f;
#pragma unroll
      for (int i = 0; i < 16; ++i) {
        const int t = tq + i * 4;
        float p = __expf(Sb[a][t] - m);
        Sb[a][t] = p;
        sm += p;
      }
      red[a][tq] = sm;
    }
    __syncthreads();

    if (tid < 49)
      l_s[tid] += red[tid][0] + red[tid][1] + red[tid][2] + red[tid][3];

    // ---- PV over this sub-tile -------------------------------------------
    {
      const float c1 = corr_s[a1];
      acc1.x *= c1; acc1.y *= c1; acc1.z *= c1; acc1.w *= c1;
#pragma unroll
      for (int tt4 = 0; tt4 < 16; ++tt4) {
        float4 p  = *(const float4*)&Sb[a1][tt4 * 4];
        float4 v0 = *(const float4*)&Vt[tt4 * 4 + 0][d41 * 4];
        float4 v1 = *(const float4*)&Vt[tt4 * 4 + 1][d41 * 4];
        float4 v2 = *(const float4*)&Vt[tt4 * 4 + 2][d41 * 4];
        float4 v3 = *(const float4*)&Vt[tt4 * 4 + 3][d41 * 4];
        acc1.x += p.x * v0.x + p.y * v1.x + p.z * v2.x + p.w * v3.x;
        acc1.y += p.x * v0.y + p.y * v1.y + p.z * v2.y + p.w * v3.y;
        acc1.z += p.x * v0.z + p.y * v1.z + p.z * v2.z + p.w * v3.z;
        acc1.w += p.x * v0.w + p.y * v1.w + p.z * v2.w + p.w * v3.w;
      }
    }
    if (has2) {
      const float c2 = corr_s[a2];
      acc2.x *= c2; acc2.y *= c2; acc2.z *= c2; acc2.w *= c2;
#pragma unroll
      for (int tt4 = 0; tt4 < 16; ++tt4) {
        float4 p  = *(const float4*)&Sb[a2][tt4 * 4];
        float4 v0 = *(const float4*)&Vt[tt4 * 4 + 0][d42 * 4];
        float4 v1 = *(const float4*)&Vt[tt4 * 4 + 1][d42 * 4];
        float4 v2 = *(const float4*)&Vt[tt4 * 4 + 2][d42 * 4];
        float4 v3 = *(const float4*)&Vt[tt4 * 4 + 3][d42 * 4];
        acc2.x += p.x * v0.x + p.y * v1.x + p.z * v2.x + p.w * v3.x;
        acc2.y += p.x * v0.y + p.y * v1.y + p.z * v2.y + p.w * v3.y;
        acc2.z += p.x * v0.z + p.y * v1.z + p.z * v2.z + p.w * v3.z;
        acc2.w += p.x * v0.w + p.y * v1.w + p.z * v2.w + p.w * v3.w;
      }
    }
    __syncthreads();   // Sb/Kt/Vt free for next sub-tile; l_s final
  }

  // ---- write unnormalized partials ---------------------------------------
  *(float4*)&pacc[((size_t)blk * 49 + a1) * 32 + d41 * 4] = acc1;
  if (has2)
    *(float4*)&pacc[((size_t)blk * 49 + a2) * 32 + d42 * 4] = acc2;
  if (tid < 49) {
    pm[(size_t)blk * 49 + tid] = m_s[tid];
    pl[(size_t)blk * 49 + tid] = l_s[tid];
  }
}

// ---- stage 1b: combine 16 chunk partials -> agent_v -----------------------
__global__ __launch_bounds__(256) void s1_reduce(
    const float* __restrict__ pacc, const float* __restrict__ pm,
    const float* __restrict__ pl, float* __restrict__ agent_v)
{
  const int bh = blockIdx.x;        // 256
  const int tid = threadIdx.x;
  const int base = bh * 16;

#pragma unroll
  for (int rep = 0; rep < 2; ++rep) {
    if (rep == 1 && tid >= 136) break;
    const int a  = (rep == 0) ? (tid >> 3) : (32 + (tid >> 3));
    const int d4 = tid & 7;
    float m = -3.0e38f;
#pragma unroll
    for (int c = 0; c < 16; ++c)
      m = fmaxf(m, pm[(size_t)(base + c) * 49 + a]);
    float l = 0.f;
    float4 acc = {0.f, 0.f, 0.f, 0.f};
#pragma unroll
    for (int c = 0; c < 16; ++c) {
      const float e = __expf(pm[(size_t)(base + c) * 49 + a] - m);
      l += pl[(size_t)(base + c) * 49 + a] * e;
      float4 p = *(const float4*)&pacc[((size_t)(base + c) * 49 + a) * 32 + d4 * 4];
      acc.x += p.x * e; acc.y += p.y * e; acc.z += p.z * e; acc.w += p.w * e;
    }
    const float inv = 1.0f / l;
    float4 o;
    o.x = acc.x * inv; o.y = acc.y * inv; o.z = acc.z * inv; o.w = acc.w * inv;
    *(float4*)&agent_v[((size_t)bh * 49 + a) * 32 + d4 * 4] = o;
  }
}

// ---- stage 2: token->agent attention + dwc 3x3 + residual -----------------
__global__ __launch_bounds__(256) void stage2(
    const float* __restrict__ q, const float* __restrict__ v,
    const float* __restrict__ qt, const float* __restrict__ agent_v,
    const float* __restrict__ bias2t, const float* __restrict__ dwc_w,
    const float* __restrict__ dwc_b, float* __restrict__ o)
{
  __shared__ float qts[49][32];
  __shared__ float avs[49][32];
  __shared__ float wcs[9][32];
  __shared__ float wb[32];

  const int tid = threadIdx.x;
  const int blk = blockIdx.x;
  const int b = blk >> 8, h = (blk >> 4) & 15, tg = blk & 15;
  const int t = tg * 256 + tid;
  const float scale = 0.17677669529663689f;

  if (tid < 196) {
#pragma unroll
    for (int rep = 0; rep < 2; ++rep) {
      int idx = tid + rep * 196;
      int a = idx >> 3, d4 = idx & 7;
      *(float4*)&qts[a][d4 * 4] =
          *(const float4*)&qt[((size_t)b * 49 + a) * 512 + h * 32 + d4 * 4];
      *(float4*)&avs[a][d4 * 4] =
          *(const float4*)&agent_v[(((size_t)b * 16 + h) * 49 + a) * 32 + d4 * 4];
    }
  }
  for (int idx = tid; idx < 288; idx += 256) {
    int j = idx >> 5, d = idx & 31;
    wcs[j][d] = dwc_w[(size_t)(h * 32 + d) * 9 + j];
  }
  if (tid < 32) wb[tid] = dwc_b[h * 32 + tid];
  __syncthreads();

  const size_t qoff = ((size_t)(b * 4096 + t)) * 512 + h * 32;
  float qr[32];
#pragma unroll
  for (int d4 = 0; d4 < 8; ++d4) {
    float4 f = *(const float4*)&q[qoff + d4 * 4];
    qr[d4 * 4 + 0] = f.x * scale; qr[d4 * 4 + 1] = f.y * scale;
    qr[d4 * 4 + 2] = f.z * scale; qr[d4 * 4 + 3] = f.w * scale;
  }

  float s[49];
  const float* b2 = bias2t + (size_t)h * 49 * 4096 + t;
#pragma unroll
  for (int a = 0; a < 49; ++a) s[a] = b2[(size_t)a * 4096];
#pragma unroll
  for (int a = 0; a < 49; ++a) {
    float acc = 0.f;
#pragma unroll
    for (int d4 = 0; d4 < 8; ++d4) {
      float4 f = *(const float4*)&qts[a][d4 * 4];
      acc += qr[d4 * 4] * f.x + qr[d4 * 4 + 1] * f.y +
             qr[d4 * 4 + 2] * f.z + qr[d4 * 4 + 3] * f.w;
    }
    s[a] += acc;
  }

  float m = -3.0e38f;
#pragma unroll
  for (int a = 0; a < 49; ++a) m = fmaxf(m, s[a]);
  float S = 0.f;
#pragma unroll
  for (int a = 0; a < 49; ++a) { s[a] = __expf(s[a] - m); S += s[a]; }
  const float inv = 1.0f / S;

  float acc[32];
#pragma unroll
  for (int d = 0; d < 32; ++d) acc[d] = wb[d];
#pragma unroll
  for (int a = 0; a < 49; ++a) {
    const float pn = s[a] * inv;
#pragma unroll
    for (int d4 = 0; d4 < 8; ++d4) {
      float4 f = *(const float4*)&avs[a][d4 * 4];
      acc[d4 * 4 + 0] += pn * f.x; acc[d4 * 4 + 1] += pn * f.y;
      acc[d4 * 4 + 2] += pn * f.z; acc[d4 * 4 + 3] += pn * f.w;
    }
  }

  const int A = t >> 6, Bc = t & 63;
#pragma unroll
  for (int widx = 0; widx < 9; ++widx) {
    const int di = widx / 3 - 1, dj = widx % 3 - 1;
    const int An = A + di, Bn = Bc + dj;
    if (An < 0 || An > 63 || Bn < 0 || Bn > 63) continue;
    const float* vr = v + ((size_t)(b * 4096) + An * 64 + Bn) * 512 + h * 32;
#pragma unroll
    for (int d4 = 0; d4 < 8; ++d4) {
      float4 f = *(const float4*)&vr[d4 * 4];
      float4 wf = *(const float4*)&wcs[widx][d4 * 4];
      acc[d4 * 4 + 0] += wf.x * f.x; acc[d4 * 4 + 1] += wf.y * f.y;
      acc[d4 * 4 + 2] += wf.z * f.z; acc[d4 * 4 + 3] += wf.w * f.w;
    }
  }

  float* orow = o + qoff;     // o aliases q: own slice fully read above
#pragma unroll
  for (int d4 = 0; d4 < 8; ++d4) {
    float4 f;
    f.x = acc[d4 * 4]; f.y = acc[d4 * 4 + 1];
    f.z = acc[d4 * 4 + 2]; f.w = acc[d4 * 4 + 3];
    *(float4*)&orow[d4 * 4] = f;
  }
}

// ---- output projection GEMM, writes final (b,C,64,64) transpose ----------
__global__ __launch_bounds__(256) void proj_gemm(
    const float* __restrict__ o, const float* __restrict__ proj_w,
    const float* __restrict__ proj_b, float* __restrict__ out)
{
  __shared__ float As[16][64];
  __shared__ float Bs[16][64];
  const int tid = threadIdx.x;
  const int tx = tid & 15, ty = tid >> 4;
  const int rowBase = blockIdx.y * 64;
  const int colBase = blockIdx.x * 64;
  const int lr = tid >> 2, lc = (tid & 3) * 4;
  const int br = tid >> 4, bc = (tid & 15) * 4;

  float acc[4][4];
#pragma unroll
  for (int i = 0; i < 4; ++i)
#pragma unroll
    for (int j = 0; j < 4; ++j) acc[i][j] = 0.f;

  for (int k0 = 0; k0 < 512; k0 += 16) {
    float4 a4 = *(const float4*)&o[(size_t)(rowBase + lr) * 512 + k0 + lc];
    As[lc + 0][lr] = a4.x; As[lc + 1][lr] = a4.y;
    As[lc + 2][lr] = a4.z; As[lc + 3][lr] = a4.w;
    *(float4*)&Bs[br][bc] =
        *(const float4*)&proj_w[(size_t)(k0 + br) * 512 + colBase + bc];
    __syncthreads();
#pragma unroll
    for (int kk = 0; kk < 16; ++kk) {
      float4 a = *(const float4*)&As[kk][ty * 4];
      float4 bv = *(const float4*)&Bs[kk][tx * 4];
      acc[0][0] += a.x * bv.x; acc[0][1] += a.x * bv.y;
      acc[0][2] += a.x * bv.z; acc[0][3] += a.x * bv.w;
      acc[1][0] += a.y * bv.x; acc[1][1] += a.y * bv.y;
      acc[1][2] += a.y * bv.z; acc[1][3] += a.y * bv.w;
      acc[2][0] += a.z * bv.x; acc[2][1] += a.z * bv.y;
      acc[2][2] += a.z * bv.z; acc[2][3] += a.z * bv.w;
      acc[3][0] += a.w * bv.x; acc[3][1] += a.w * bv.y;
      acc[3][2] += a.w * bv.z; acc[3][3] += a.w * bv.w;
    }
    __syncthreads();
  }

  const int b = rowBase >> 12;
  const int t0 = (rowBase & 4095) + ty * 4;
#pragma unroll
  for (int j = 0; j < 4; ++j) {
    const int gc = colBase + tx * 4 + j;
    const float pb = proj_b[gc];
    float4 wv;
    wv.x = acc[0][j] + pb; wv.y = acc[1][j] + pb;
    wv.z = acc[2][j] + pb; wv.w = acc[3][j] + pb;
    *(float4*)&out[((size_t)(b * 512 + gc)) * 4096 + t0] = wv;
  }
}

// ---------------------------------------------------------------------------
extern "C" void kernel_launch(void* const* d_in, const int* in_sizes, int n_in,
                              void* d_out, int out_size, void* d_ws, size_t ws_size,
                              hipStream_t stream)
{
  (void)in_sizes; (void)n_in; (void)out_size; (void)ws_size;
  const float* x      = (const float*)d_in[0];
  const float* in_w   = (const float*)d_in[1];
  const float* in_b   = (const float*)d_in[2];
  const float* qkv_w  = (const float*)d_in[3];
  const float* qkv_b  = (const float*)d_in[4];
  const float* proj_w = (const float*)d_in[5];
  const float* proj_b = (const float*)d_in[6];
  const float* dwc_w  = (const float*)d_in[7];
  const float* dwc_b  = (const float*)d_in[8];
  const float* an_b   = (const float*)d_in[9];
  const float* na_b   = (const float*)d_in[10];
  const float* ah_b   = (const float*)d_in[11];
  const float* aw_b   = (const float*)d_in[12];
  const float* ha_b   = (const float*)d_in[13];
  const float* wa_b   = (const float*)d_in[14];
  float* out = (float*)d_out;

  float* q     = (float*)d_ws;               // 33,554,432 f32
  float* kbuf  = q + 33554432ull;            // 33,554,432
  float* vbuf  = kbuf + 33554432ull;         // 33,554,432
  float* qt    = vbuf + 33554432ull;         // 401,408
  float* agv   = qt + 401408ull;             // 401,408
  float* bias1 = agv + 401408ull;            // 3,211,264
  float* bias2t= bias1 + 3211264ull;         // 3,211,264
  float* o     = q;                          // alias (per-thread RAW only)

  // stage1 partials parked in d_out (fully overwritten later by proj_gemm)
  float* pacc = out;                         // 4096*49*32 = 6,422,528
  float* pm   = pacc + 6422528ull;           // 200,704
  float* pl   = pm + 200704ull;              // 200,704

  qkv_gemm<<<dim3(24, 1024), 256, 0, stream>>>(x, in_w, in_b, qkv_w, qkv_b,
                                               q, kbuf, vbuf);
  pool_qt<<<784, 256, 0, stream>>>(q, qt);
  bias_prep<<<784, 256, 0, stream>>>(an_b, na_b, ah_b, aw_b, ha_b, wa_b,
                                     bias1, bias2t);
  s1_partial<<<4096, 256, 0, stream>>>(qt, kbuf, vbuf, bias1, pacc, pm, pl);
  s1_reduce<<<256, 256, 0, stream>>>(pacc, pm, pl, agv);
  stage2<<<4096, 256, 0, stream>>>(q, vbuf, qt, agv, bias2t, dwc_w, dwc_b, o);
  proj_gemm<<<dim3(8, 1024), 256, 0, stream>>>(o, proj_w, proj_b, out);
}

// Round 6
// 1327.031 us; speedup vs baseline: 4.5981x; 2.1308x over previous
//
#include <hip/hip_runtime.h>

// ---------------------------------------------------------------------------
// AgentAttention forward. B=16, CIN=3, H=W=64, n=4096, C=512, NH=16, hd=32,
// AGENT=49. token t = w*64 + h ; grid axes A1 = t>>6, A2 = t&63.
// GEMMs in bf16 MFMA (16x16x32), everything else f32.
// ---------------------------------------------------------------------------

typedef unsigned short u16;
typedef __attribute__((ext_vector_type(8))) short bf16x8;
typedef __attribute__((ext_vector_type(4))) float f32x4;

__device__ __forceinline__ u16 f2bf(float f) {          // RNE f32 -> bf16
  unsigned int u = __float_as_uint(f);
  unsigned int r = (u + 0x7fffu + ((u >> 16) & 1u)) >> 16;
  return (u16)r;
}

__device__ __forceinline__ void gload16(const void* g, void* l) {
  __builtin_amdgcn_global_load_lds(
      (const __attribute__((address_space(1))) unsigned int*)g,
      (__attribute__((address_space(3))) unsigned int*)l, 16, 0, 0);
}

// ---- prep: A_bf[b*4096+t][512] = bf16(in_b + x @ in_w) --------------------
__global__ __launch_bounds__(256) void prep_abf(
    const float* __restrict__ x, const float* __restrict__ in_w,
    const float* __restrict__ in_b, u16* __restrict__ abf)
{
  const int idx = blockIdx.x * 256 + threadIdx.x;
  const int row = idx >> 6, c8 = (idx & 63) << 3;
  const int b = row >> 12, t = row & 4095;
  const int sp = ((t & 63) << 6) | (t >> 6);
  const float x0 = x[(size_t)(b * 3 + 0) * 4096 + sp];
  const float x1 = x[(size_t)(b * 3 + 1) * 4096 + sp];
  const float x2 = x[(size_t)(b * 3 + 2) * 4096 + sp];
  union { u16 us[8]; uint4 v; } pk;
#pragma unroll
  for (int j = 0; j < 8; ++j) {
    const int c = c8 + j;
    float a = in_b[c] + x0 * in_w[c] + x1 * in_w[512 + c] + x2 * in_w[1024 + c];
    pk.us[j] = f2bf(a);
  }
  *(uint4*)&abf[(size_t)row * 512 + c8] = pk.v;
}

// ---- prep: Bt[n][k] = bf16(W[k][n]) ; 32x32 LDS tiles ---------------------
__global__ __launch_bounds__(256) void wT(
    const float* __restrict__ W, u16* __restrict__ Bt, int K, int N)
{
  __shared__ float T[32][33];
  const int tid = threadIdx.x;
  const int n0 = blockIdx.x * 32, k0 = blockIdx.y * 32;
  const int tx = tid & 31, ty = tid >> 5;
#pragma unroll
  for (int i = 0; i < 4; ++i) {
    const int k = ty + i * 8;
    T[k][tx] = W[(size_t)(k0 + k) * N + n0 + tx];
  }
  __syncthreads();
#pragma unroll
  for (int i = 0; i < 4; ++i) {
    const int n = ty + i * 8;
    Bt[(size_t)(n0 + n) * K + k0 + tx] = f2bf(T[tx][n]);
  }
}

// ---- bf16 MFMA GEMM: C[65536 x 1536] = A[65536 x 512] @ Bt^T --------------
// 128x128 tile, BK=64, gload_lds staging, XOR-swizzled LDS (T2, both-sides).
__global__ __launch_bounds__(256) void qkv_mfma(
    const u16* __restrict__ Abf, const u16* __restrict__ Btw,
    const float* __restrict__ qkv_b,
    float* __restrict__ q, float* __restrict__ k, float* __restrict__ v)
{
  __shared__ u16 As[128 * 64];
  __shared__ u16 Bs[128 * 64];
  const int tid = threadIdx.x;
  const int w = tid >> 6, lane = tid & 63;
  const int wr = w >> 1, wc = w & 1;
  const int g = lane >> 4, lr = lane & 15;
  const int rowBase = blockIdx.y * 128, colBase = blockIdx.x * 128;
  const int lr8 = lane >> 3, lp = lane & 7;
  const int swz = lp ^ lr8;                 // staging source slot

  f32x4 acc[4][4] = {};
  const u16* Ag = Abf + (size_t)rowBase * 512;
  const u16* Bg = Btw + (size_t)colBase * 512;

  for (int s = 0; s < 8; ++s) {
    const int k0 = s * 64;
    if (s) __syncthreads();
#pragma unroll
    for (int i = 0; i < 4; ++i) {
      const int ch = w * 4 + i;
      const int r = ch * 8 + lr8;
      gload16(Ag + (size_t)r * 512 + k0 + swz * 8, (char*)As + ch * 1024);
      gload16(Bg + (size_t)r * 512 + k0 + swz * 8, (char*)Bs + ch * 1024);
    }
    __syncthreads();
#pragma unroll
    for (int kk = 0; kk < 2; ++kk) {
      bf16x8 af[4], bfr[4];
      const int sl = kk * 4 + g;
      const int ps = (sl ^ (lr & 7)) * 16;  // swizzled 16B slot
#pragma unroll
      for (int f = 0; f < 4; ++f) {
        af[f]  = *(const bf16x8*)((const char*)As + (wr * 64 + f * 16 + lr) * 128 + ps);
        bfr[f] = *(const bf16x8*)((const char*)Bs + (wc * 64 + f * 16 + lr) * 128 + ps);
      }
#pragma unroll
      for (int fr = 0; fr < 4; ++fr)
#pragma unroll
        for (int fc = 0; fc < 4; ++fc)
          acc[fr][fc] = __builtin_amdgcn_mfma_f32_16x16x32_bf16(
              af[fr], bfr[fc], acc[fr][fc], 0, 0, 0);
    }
  }

  // epilogue: C row = rowBase+wr*64+fr*16+4g+i, col = colBase+wc*64+fc*16+lr
#pragma unroll
  for (int fc = 0; fc < 4; ++fc) {
    const int gc = colBase + wc * 64 + fc * 16 + lr;
    float* dst; int lc0;
    if (gc < 512)       { dst = q; lc0 = gc; }
    else if (gc < 1024) { dst = k; lc0 = gc - 512; }
    else                { dst = v; lc0 = gc - 1024; }
    const float pb = qkv_b[gc];
#pragma unroll
    for (int fr = 0; fr < 4; ++fr) {
      const int R0 = rowBase + wr * 64 + fr * 16 + 4 * g;
#pragma unroll
      for (int i = 0; i < 4; ++i)
        dst[(size_t)(R0 + i) * 512 + lc0] = acc[fr][fc][i] + pb;
    }
  }
}

// ---- bf16 MFMA GEMM: out[b][gc][t] = obf[b*4096+t][:] @ proj_w[:, gc] -----
__global__ __launch_bounds__(256) void proj_mfma(
    const u16* __restrict__ Abf, const u16* __restrict__ Btw,
    const float* __restrict__ proj_b, float* __restrict__ out)
{
  __shared__ u16 As[128 * 64];
  __shared__ u16 Bs[128 * 64];
  const int tid = threadIdx.x;
  const int w = tid >> 6, lane = tid & 63;
  const int wr = w >> 1, wc = w & 1;
  const int g = lane >> 4, lr = lane & 15;
  const int rowBase = blockIdx.y * 128, colBase = blockIdx.x * 128;
  const int lr8 = lane >> 3, lp = lane & 7;
  const int swz = lp ^ lr8;

  f32x4 acc[4][4] = {};
  const u16* Ag = Abf + (size_t)rowBase * 512;
  const u16* Bg = Btw + (size_t)colBase * 512;

  for (int s = 0; s < 8; ++s) {
    const int k0 = s * 64;
    if (s) __syncthreads();
#pragma unroll
    for (int i = 0; i < 4; ++i) {
      const int ch = w * 4 + i;
      const int r = ch * 8 + lr8;
      gload16(Ag + (size_t)r * 512 + k0 + swz * 8, (char*)As + ch * 1024);
      gload16(Bg + (size_t)r * 512 + k0 + swz * 8, (char*)Bs + ch * 1024);
    }
    __syncthreads();
#pragma unroll
    for (int kk = 0; kk < 2; ++kk) {
      bf16x8 af[4], bfr[4];
      const int sl = kk * 4 + g;
      const int ps = (sl ^ (lr & 7)) * 16;
#pragma unroll
      for (int f = 0; f < 4; ++f) {
        af[f]  = *(const bf16x8*)((const char*)As + (wr * 64 + f * 16 + lr) * 128 + ps);
        bfr[f] = *(const bf16x8*)((const char*)Bs + (wc * 64 + f * 16 + lr) * 128 + ps);
      }
#pragma unroll
      for (int fr = 0; fr < 4; ++fr)
#pragma unroll
        for (int fc = 0; fc < 4; ++fc)
          acc[fr][fc] = __builtin_amdgcn_mfma_f32_16x16x32_bf16(
              af[fr], bfr[fc], acc[fr][fc], 0, 0, 0);
    }
  }

  const int b = rowBase >> 12;
#pragma unroll
  for (int fc = 0; fc < 4; ++fc) {
    const int gc = colBase + wc * 64 + fc * 16 + lr;
    const float pb = proj_b[gc];
    float* obase = out + (size_t)(b * 512 + gc) * 4096;
#pragma unroll
    for (int fr = 0; fr < 4; ++fr) {
      const int t0 = (rowBase & 4095) + wr * 64 + fr * 16 + 4 * g;
      float4 val;
      val.x = acc[fr][fc][0] + pb; val.y = acc[fr][fc][1] + pb;
      val.z = acc[fr][fc][2] + pb; val.w = acc[fr][fc][3] + pb;
      *(float4*)&obase[t0] = val;
    }
  }
}

// ---- adaptive avg pool q -> qt (b,49,512) ---------------------------------
__global__ __launch_bounds__(256) void pool_qt(const float* __restrict__ q,
                                               float* __restrict__ qt)
{
  const int blk = blockIdx.x;
  const int a = blk % 49, b = blk / 49;
  const int iA = a / 7, iB = a % 7;
  const int sA = (iA * 64) / 7, eA = ((iA + 1) * 64 + 6) / 7;
  const int sB = (iB * 64) / 7, eB = ((iB + 1) * 64 + 6) / 7;
  const float invn = 1.0f / (float)((eA - sA) * (eB - sB));
  for (int c = threadIdx.x; c < 512; c += 256) {
    float s = 0.f;
    for (int A = sA; A < eA; ++A)
      for (int Bb = sB; Bb < eB; ++Bb)
        s += q[((size_t)b * 4096 + A * 64 + Bb) * 512 + c];
    qt[((size_t)b * 49 + a) * 512 + c] = s * invn;
  }
}

// ---- bias precompute ------------------------------------------------------
__global__ __launch_bounds__(256) void bias_prep(
    const float* __restrict__ an, const float* __restrict__ na,
    const float* __restrict__ ah, const float* __restrict__ aw,
    const float* __restrict__ ha, const float* __restrict__ wa,
    float* __restrict__ bias1, float* __restrict__ bias2t)
{
  const int blk = blockIdx.x;
  const int a = blk % 49, h = blk / 49;
  const float* anp = an + (size_t)(h * 49 + a) * 49;
  const float* nap = na + (size_t)(h * 49 + a) * 49;
  for (int t = threadIdx.x; t < 4096; t += 256) {
    const int tA = t >> 6, tB = t & 63;
    float cA = (tA + 0.5f) * 0.109375f - 0.5f;
    cA = fminf(fmaxf(cA, 0.f), 6.f);
    int i0A = (int)floorf(cA); float wA = cA - (float)i0A;
    int i1A = min(i0A + 1, 6);
    float cB = (tB + 0.5f) * 0.109375f - 0.5f;
    cB = fminf(fmaxf(cB, 0.f), 6.f);
    int i0B = (int)floorf(cB); float wB = cB - (float)i0B;
    int i1B = min(i0B + 1, 6);

    float v1 = (1.f - wA) * ((1.f - wB) * anp[i0A * 7 + i0B] + wB * anp[i0A * 7 + i1B]) +
               wA        * ((1.f - wB) * anp[i1A * 7 + i0B] + wB * anp[i1A * 7 + i1B]);
    float v2 = (1.f - wA) * ((1.f - wB) * nap[i0A * 7 + i0B] + wB * nap[i0A * 7 + i1B]) +
               wA        * ((1.f - wB) * nap[i1A * 7 + i0B] + wB * nap[i1A * 7 + i1B]);

    bias1[((size_t)h * 49 + a) * 4096 + t] =
        v1 + ah[(size_t)(h * 49 + a) * 64 + tA] + aw[(size_t)(h * 49 + a) * 64 + tB];
    bias2t[((size_t)h * 49 + a) * 4096 + t] =
        v2 + ha[((size_t)h * 64 + tA) * 49 + a] + wa[((size_t)h * 64 + tB) * 49 + a];
  }
}

// ---- stage 1a: split-K flash partials. grid = (b,h,chunk16) = 4096 --------
__global__ __launch_bounds__(256) void s1_partial(
    const float* __restrict__ qt, const float* __restrict__ k,
    const float* __restrict__ v, const float* __restrict__ bias1,
    float* __restrict__ pacc, float* __restrict__ pm, float* __restrict__ pl)
{
  __shared__ float qts[49][32];
  __shared__ float Kt[64][36];
  __shared__ float Vt[64][36];
  __shared__ float Sb[49][68];
  __shared__ float m_s[56], l_s[56], corr_s[56];
  __shared__ float red[49][4];

  const int blk = blockIdx.x;
  const int c  = blk & 15;
  const int bh = blk >> 4;
  const int h = bh & 15, b = bh >> 4;
  const int tid = threadIdx.x;
  const float scale = 0.17677669529663689f;

  if (tid < 196) {
#pragma unroll
    for (int rep = 0; rep < 2; ++rep) {
      int idx = tid + rep * 196;
      int aa = idx >> 3, d4 = idx & 7;
      float4 f = *(const float4*)&qt[((size_t)b * 49 + aa) * 512 + h * 32 + d4 * 4];
      f.x *= scale; f.y *= scale; f.z *= scale; f.w *= scale;
      *(float4*)&qts[aa][d4 * 4] = f;
    }
  }
  if (tid < 56) { m_s[tid] = -3.0e38f; l_s[tid] = 0.f; corr_s[tid] = 1.f; }
  __syncthreads();

  const int a  = tid >> 2, tq = tid & 3;
  float qsr[32];
  if (tid < 196) {
#pragma unroll
    for (int d4 = 0; d4 < 8; ++d4) {
      float4 f = *(const float4*)&qts[a][d4 * 4];
      qsr[d4 * 4 + 0] = f.x; qsr[d4 * 4 + 1] = f.y;
      qsr[d4 * 4 + 2] = f.z; qsr[d4 * 4 + 3] = f.w;
    }
  }

  const int a1 = tid >> 3, d41 = tid & 7;
  const int a2 = 32 + (tid >> 3), d42 = tid & 7;
  const bool has2 = (tid < 136);
  float4 acc1 = {0.f, 0.f, 0.f, 0.f};
  float4 acc2 = {0.f, 0.f, 0.f, 0.f};

  const float* kbase = k + (size_t)b * 4096 * 512 + h * 32;
  const float* vbase = v + (size_t)b * 4096 * 512 + h * 32;
  const float* bbase = bias1 + (size_t)(h * 49) * 4096 + c * 256;

  for (int st = 0; st < 4; ++st) {
    const int t0 = st * 64;
#pragma unroll
    for (int i = 0; i < 2; ++i) {
      int idx = tid + i * 256;
      int r = idx >> 3, d4 = idx & 7;
      size_t go = (size_t)(c * 256 + t0 + r) * 512 + d4 * 4;
      *(float4*)&Kt[r][d4 * 4] = *(const float4*)&kbase[go];
      *(float4*)&Vt[r][d4 * 4] = *(const float4*)&vbase[go];
    }
    for (int idx = tid; idx < 784; idx += 256) {
      int aa = idx >> 4, d16 = idx & 15;
      *(float4*)&Sb[aa][d16 * 4] =
          *(const float4*)&bbase[(size_t)aa * 4096 + t0 + d16 * 4];
    }
    __syncthreads();

    if (tid < 196) {
      float mloc = -3.0e38f;
#pragma unroll
      for (int i = 0; i < 16; ++i) {
        const int t = tq + i * 4;
        float s = Sb[a][t];
#pragma unroll
        for (int d4 = 0; d4 < 8; ++d4) {
          float4 kf = *(const float4*)&Kt[t][d4 * 4];
          s += qsr[d4 * 4] * kf.x + qsr[d4 * 4 + 1] * kf.y +
               qsr[d4 * 4 + 2] * kf.z + qsr[d4 * 4 + 3] * kf.w;
        }
        Sb[a][t] = s;
        mloc = fmaxf(mloc, s);
      }
      red[a][tq] = mloc;
    }
    __syncthreads();

    if (tid < 49) {
      float mo = m_s[tid];
      float mx = fmaxf(fmaxf(red[tid][0], red[tid][1]),
                       fmaxf(red[tid][2], red[tid][3]));
      mx = fmaxf(mx, mo);
      float cc = __expf(mo - mx);
      m_s[tid] = mx; corr_s[tid] = cc; l_s[tid] *= cc;
    }
    __syncthreads();

    if (tid < 196) {
      const float m = m_s[a];
      float sm = 0.f;
#pragma unroll
      for (int i = 0; i < 16; ++i) {
        const int t = tq + i * 4;
        float p = __expf(Sb[a][t] - m);
        Sb[a][t] = p;
        sm += p;
      }
      red[a][tq] = sm;
    }
    __syncthreads();

    if (tid < 49)
      l_s[tid] += red[tid][0] + red[tid][1] + red[tid][2] + red[tid][3];

    {
      const float c1 = corr_s[a1];
      acc1.x *= c1; acc1.y *= c1; acc1.z *= c1; acc1.w *= c1;
#pragma unroll
      for (int tt4 = 0; tt4 < 16; ++tt4) {
        float4 p  = *(const float4*)&Sb[a1][tt4 * 4];
        float4 v0 = *(const float4*)&Vt[tt4 * 4 + 0][d41 * 4];
        float4 v1 = *(const float4*)&Vt[tt4 * 4 + 1][d41 * 4];
        float4 v2 = *(const float4*)&Vt[tt4 * 4 + 2][d41 * 4];
        float4 v3 = *(const float4*)&Vt[tt4 * 4 + 3][d41 * 4];
        acc1.x += p.x * v0.x + p.y * v1.x + p.z * v2.x + p.w * v3.x;
        acc1.y += p.x * v0.y + p.y * v1.y + p.z * v2.y + p.w * v3.y;
        acc1.z += p.x * v0.z + p.y * v1.z + p.z * v2.z + p.w * v3.z;
        acc1.w += p.x * v0.w + p.y * v1.w + p.z * v2.w + p.w * v3.w;
      }
    }
    if (has2) {
      const float c2 = corr_s[a2];
      acc2.x *= c2; acc2.y *= c2; acc2.z *= c2; acc2.w *= c2;
#pragma unroll
      for (int tt4 = 0; tt4 < 16; ++tt4) {
        float4 p  = *(const float4*)&Sb[a2][tt4 * 4];
        float4 v0 = *(const float4*)&Vt[tt4 * 4 + 0][d42 * 4];
        float4 v1 = *(const float4*)&Vt[tt4 * 4 + 1][d42 * 4];
        float4 v2 = *(const float4*)&Vt[tt4 * 4 + 2][d42 * 4];
        float4 v3 = *(const float4*)&Vt[tt4 * 4 + 3][d42 * 4];
        acc2.x += p.x * v0.x + p.y * v1.x + p.z * v2.x + p.w * v3.x;
        acc2.y += p.x * v0.y + p.y * v1.y + p.z * v2.y + p.w * v3.y;
        acc2.z += p.x * v0.z + p.y * v1.z + p.z * v2.z + p.w * v3.z;
        acc2.w += p.x * v0.w + p.y * v1.w + p.z * v2.w + p.w * v3.w;
      }
    }
    __syncthreads();
  }

  *(float4*)&pacc[((size_t)blk * 49 + a1) * 32 + d41 * 4] = acc1;
  if (has2)
    *(float4*)&pacc[((size_t)blk * 49 + a2) * 32 + d42 * 4] = acc2;
  if (tid < 49) {
    pm[(size_t)blk * 49 + tid] = m_s[tid];
    pl[(size_t)blk * 49 + tid] = l_s[tid];
  }
}

// ---- stage 1b: combine 16 chunk partials -> agent_v -----------------------
__global__ __launch_bounds__(256) void s1_reduce(
    const float* __restrict__ pacc, const float* __restrict__ pm,
    const float* __restrict__ pl, float* __restrict__ agent_v)
{
  const int bh = blockIdx.x;
  const int tid = threadIdx.x;
  const int base = bh * 16;

#pragma unroll
  for (int rep = 0; rep < 2; ++rep) {
    if (rep == 1 && tid >= 136) break;
    const int a  = (rep == 0) ? (tid >> 3) : (32 + (tid >> 3));
    const int d4 = tid & 7;
    float m = -3.0e38f;
#pragma unroll
    for (int c = 0; c < 16; ++c)
      m = fmaxf(m, pm[(size_t)(base + c) * 49 + a]);
    float l = 0.f;
    float4 acc = {0.f, 0.f, 0.f, 0.f};
#pragma unroll
    for (int c = 0; c < 16; ++c) {
      const float e = __expf(pm[(size_t)(base + c) * 49 + a] - m);
      l += pl[(size_t)(base + c) * 49 + a] * e;
      float4 p = *(const float4*)&pacc[((size_t)(base + c) * 49 + a) * 32 + d4 * 4];
      acc.x += p.x * e; acc.y += p.y * e; acc.z += p.z * e; acc.w += p.w * e;
    }
    const float inv = 1.0f / l;
    float4 o;
    o.x = acc.x * inv; o.y = acc.y * inv; o.z = acc.z * inv; o.w = acc.w * inv;
    *(float4*)&agent_v[((size_t)bh * 49 + a) * 32 + d4 * 4] = o;
  }
}

// ---- stage 2: token->agent attention + dwc 3x3 + residual; bf16 out -------
__global__ __launch_bounds__(256) void stage2(
    const float* __restrict__ q, const float* __restrict__ v,
    const float* __restrict__ qt, const float* __restrict__ agent_v,
    const float* __restrict__ bias2t, const float* __restrict__ dwc_w,
    const float* __restrict__ dwc_b, u16* __restrict__ obf)
{
  __shared__ float qts[49][32];
  __shared__ float avs[49][32];
  __shared__ float wcs[9][32];
  __shared__ float wb[32];

  const int tid = threadIdx.x;
  const int blk = blockIdx.x;
  const int b = blk >> 8, h = (blk >> 4) & 15, tg = blk & 15;
  const int t = tg * 256 + tid;
  const float scale = 0.17677669529663689f;

  if (tid < 196) {
#pragma unroll
    for (int rep = 0; rep < 2; ++rep) {
      int idx = tid + rep * 196;
      int a = idx >> 3, d4 = idx & 7;
      *(float4*)&qts[a][d4 * 4] =
          *(const float4*)&qt[((size_t)b * 49 + a) * 512 + h * 32 + d4 * 4];
      *(float4*)&avs[a][d4 * 4] =
          *(const float4*)&agent_v[(((size_t)b * 16 + h) * 49 + a) * 32 + d4 * 4];
    }
  }
  for (int idx = tid; idx < 288; idx += 256) {
    int j = idx >> 5, d = idx & 31;
    wcs[j][d] = dwc_w[(size_t)(h * 32 + d) * 9 + j];
  }
  if (tid < 32) wb[tid] = dwc_b[h * 32 + tid];
  __syncthreads();

  const size_t qoff = ((size_t)(b * 4096 + t)) * 512 + h * 32;
  float qr[32];
#pragma unroll
  for (int d4 = 0; d4 < 8; ++d4) {
    float4 f = *(const float4*)&q[qoff + d4 * 4];
    qr[d4 * 4 + 0] = f.x * scale; qr[d4 * 4 + 1] = f.y * scale;
    qr[d4 * 4 + 2] = f.z * scale; qr[d4 * 4 + 3] = f.w * scale;
  }

  float s[49];
  const float* b2 = bias2t + (size_t)h * 49 * 4096 + t;
#pragma unroll
  for (int a = 0; a < 49; ++a) s[a] = b2[(size_t)a * 4096];
#pragma unroll
  for (int a = 0; a < 49; ++a) {
    float acc = 0.f;
#pragma unroll
    for (int d4 = 0; d4 < 8; ++d4) {
      float4 f = *(const float4*)&qts[a][d4 * 4];
      acc += qr[d4 * 4] * f.x + qr[d4 * 4 + 1] * f.y +
             qr[d4 * 4 + 2] * f.z + qr[d4 * 4 + 3] * f.w;
    }
    s[a] += acc;
  }

  float m = -3.0e38f;
#pragma unroll
  for (int a = 0; a < 49; ++a) m = fmaxf(m, s[a]);
  float S = 0.f;
#pragma unroll
  for (int a = 0; a < 49; ++a) { s[a] = __expf(s[a] - m); S += s[a]; }
  const float inv = 1.0f / S;

  float acc[32];
#pragma unroll
  for (int d = 0; d < 32; ++d) acc[d] = wb[d];
#pragma unroll
  for (int a = 0; a < 49; ++a) {
    const float pn = s[a] * inv;
#pragma unroll
    for (int d4 = 0; d4 < 8; ++d4) {
      float4 f = *(const float4*)&avs[a][d4 * 4];
      acc[d4 * 4 + 0] += pn * f.x; acc[d4 * 4 + 1] += pn * f.y;
      acc[d4 * 4 + 2] += pn * f.z; acc[d4 * 4 + 3] += pn * f.w;
    }
  }

  const int A = t >> 6, Bc = t & 63;
#pragma unroll
  for (int widx = 0; widx < 9; ++widx) {
    const int di = widx / 3 - 1, dj = widx % 3 - 1;
    const int An = A + di, Bn = Bc + dj;
    if (An < 0 || An > 63 || Bn < 0 || Bn > 63) continue;
    const float* vr = v + ((size_t)(b * 4096) + An * 64 + Bn) * 512 + h * 32;
#pragma unroll
    for (int d4 = 0; d4 < 8; ++d4) {
      float4 f = *(const float4*)&vr[d4 * 4];
      float4 wf = *(const float4*)&wcs[widx][d4 * 4];
      acc[d4 * 4 + 0] += wf.x * f.x; acc[d4 * 4 + 1] += wf.y * f.y;
      acc[d4 * 4 + 2] += wf.z * f.z; acc[d4 * 4 + 3] += wf.w * f.w;
    }
  }

  u16* orow = obf + qoff;
#pragma unroll
  for (int d8 = 0; d8 < 4; ++d8) {
    union { u16 us[8]; uint4 vec; } pk;
#pragma unroll
    for (int j = 0; j < 8; ++j) pk.us[j] = f2bf(acc[d8 * 8 + j]);
    *(uint4*)&orow[d8 * 8] = pk.vec;
  }
}

// ---------------------------------------------------------------------------
extern "C" void kernel_launch(void* const* d_in, const int* in_sizes, int n_in,
                              void* d_out, int out_size, void* d_ws, size_t ws_size,
                              hipStream_t stream)
{
  (void)in_sizes; (void)n_in; (void)out_size; (void)ws_size;
  const float* x      = (const float*)d_in[0];
  const float* in_w   = (const float*)d_in[1];
  const float* in_b   = (const float*)d_in[2];
  const float* qkv_w  = (const float*)d_in[3];
  const float* qkv_b  = (const float*)d_in[4];
  const float* proj_w = (const float*)d_in[5];
  const float* proj_b = (const float*)d_in[6];
  const float* dwc_w  = (const float*)d_in[7];
  const float* dwc_b  = (const float*)d_in[8];
  const float* an_b   = (const float*)d_in[9];
  const float* na_b   = (const float*)d_in[10];
  const float* ah_b   = (const float*)d_in[11];
  const float* aw_b   = (const float*)d_in[12];
  const float* ha_b   = (const float*)d_in[13];
  const float* wa_b   = (const float*)d_in[14];
  float* out = (float*)d_out;

  float* q      = (float*)d_ws;              // 33,554,432 f32
  float* kbuf   = q + 33554432ull;           // 33,554,432
  float* vbuf   = kbuf + 33554432ull;        // 33,554,432
  float* qt     = vbuf + 33554432ull;        // 401,408
  float* agv    = qt + 401408ull;            // 401,408
  float* bias1  = agv + 401408ull;           // 3,211,264
  float* bias2t = bias1 + 3211264ull;        // 3,211,264
  u16*   wbf_q  = (u16*)(bias2t + 3211264ull);   // 786,432 u16 (Bt qkv)
  u16*   wbf_p  = wbf_q + 786432ull;             // 262,144 u16 (Bt proj)

  // d_out juggling (all uses strictly serialized on stream):
  //   [0] A_bf (64MB, dead after qkv_mfma) -> [1] s1 partials (27MB, dead
  //   after s1_reduce) -> [2] final out (128MB, written by proj_mfma).
  u16*   abf  = (u16*)d_out;
  float* pacc = out;                         // 4096*49*32 = 6,422,528
  float* pm   = pacc + 6422528ull;           // 200,704
  float* pl   = pm + 200704ull;              // 200,704
  u16*   obf  = (u16*)kbuf;                  // k dead after s1_partial

  prep_abf<<<16384, 256, 0, stream>>>(x, in_w, in_b, abf);
  wT<<<dim3(48, 16), 256, 0, stream>>>(qkv_w, wbf_q, 512, 1536);
  wT<<<dim3(16, 16), 256, 0, stream>>>(proj_w, wbf_p, 512, 512);
  qkv_mfma<<<dim3(12, 512), 256, 0, stream>>>(abf, wbf_q, qkv_b, q, kbuf, vbuf);
  pool_qt<<<784, 256, 0, stream>>>(q, qt);
  bias_prep<<<784, 256, 0, stream>>>(an_b, na_b, ah_b, aw_b, ha_b, wa_b,
                                     bias1, bias2t);
  s1_partial<<<4096, 256, 0, stream>>>(qt, kbuf, vbuf, bias1, pacc, pm, pl);
  s1_reduce<<<256, 256, 0, stream>>>(pacc, pm, pl, agv);
  stage2<<<4096, 256, 0, stream>>>(q, vbuf, qt, agv, bias2t, dwc_w, dwc_b, obf);
  proj_mfma<<<dim3(4, 512), 256, 0, stream>>>(obf, wbf_p, proj_b, out);
}